// Round 4
// baseline (304.310 us; speedup 1.0000x reference)
//
#include <hip/hip_runtime.h>
#include <hip/hip_bf16.h>

// MultiAttentionHead: B=2, T=2048, E=1024, H=16, D=64
// Inputs (fp32): x[B,T,E], Wq[H,E,D], Wk[H,E,D], Wv[H,E,D], Wo[E,E]
// Output (fp32): combined @ Wo + x   [B,T,E]
//
// ws layout (ushort=fp16 elements):
//   xh/comb : 0        .. 4M    (x fp16, later overwritten by attn output)
//   wt      : 4M       .. 7.34M ([p][h][d][e] transposed QKV weights)
//   wot     : 7.34M    .. 8.39M ([j][e] transposed Wo)
//   q : 8.39M  k : 12.58M  vt : 16.78M .. 21.24M  (total ~42.5 MB)
//
// r10: GEMM fragment gathers stage through LDS with lane-contiguous loads.
// r11: attn softmax fully in-register (swapped QK^T -> S^T lane-local rows;
//      exp'd values are directly the 16x16x16 PV A-fragment).
// r12: KVBLK=128 single-buffer, defer-max rescale (THR=8), XCD-bijective
//      block swizzle, split K/V prefetch, cvt_pkrtz P packing.
// r14 (this round): fix the r12 scratch spill. Root cause: PV accumulator
//      accessed via pointer-select over address-taken locals (o0..o3) under
//      higher register pressure + the defer-max branch -> mem2reg failed ->
//      every MFMA did scratch R/W (WRITE_SIZE 8MB -> 488MB). Now f32x4 o[4]
//      with static unrolled indices only; launch_bounds(256) (no min-wave
//      cap) so the allocator can take ~120 VGPRs cleanly.

#define B_ 2
#define T_ 2048
#define E_ 1024
#define H_ 16
#define D_ 64
#define VTS_ 2176   // padded vt leading dim (elements)
#define LD_ 72      // LDS tile row stride for GEMM staging (64 + 8)
#define KV_ 128     // attn keys per tile
#define LDK_ 72     // attn K-tile row stride (64 + 8)
#define LDV_ 144    // attn V-tile row stride (128 + 16; uniform b64 banks)
#define NTILE_ (T_ / KV_)

typedef _Float16 h8 __attribute__((ext_vector_type(8)));
typedef _Float16 h4 __attribute__((ext_vector_type(4)));
typedef __fp16  pk2 __attribute__((ext_vector_type(2)));
typedef float f32x4 __attribute__((ext_vector_type(4)));

union U4 { uint4 u; h8 h; };
union PK4 { pk2 p[2]; h4 h; };

__device__ __forceinline__ float h2f(unsigned short s) {
  _Float16 h;
  __builtin_memcpy(&h, &s, 2);
  return (float)h;
}

__device__ __forceinline__ unsigned short f2h(float f) {
  _Float16 h = (_Float16)f;
  unsigned short s;
  __builtin_memcpy(&s, &h, 2);
  return s;
}

// ---------------------------------------------------------------------------
// Prep 0: x fp32 -> fp16.  grid = B*T*E/1024, block=256.
// ---------------------------------------------------------------------------
__global__ __launch_bounds__(256) void cvt_x(const float* __restrict__ x,
                                             unsigned short* __restrict__ xh) {
  const size_t i = ((size_t)blockIdx.x * 256 + threadIdx.x) * 4;
  const float4 f = *(const float4*)(x + i);
  ushort4 pk;
  pk.x = f2h(f.x); pk.y = f2h(f.y); pk.z = f2h(f.z); pk.w = f2h(f.w);
  *(ushort4*)(xh + i) = pk;
}

// ---------------------------------------------------------------------------
// Prep 1: Wq/Wk/Wv [h][e][d] fp32 -> wt [p][h][d][e] fp16. grid=(16,16,3).
// ---------------------------------------------------------------------------
__global__ __launch_bounds__(256) void tconv_w(
    const float* __restrict__ Wq, const float* __restrict__ Wk,
    const float* __restrict__ Wv, unsigned short* __restrict__ wt) {
  __shared__ float ts[64][65];
  const int p = blockIdx.z, h = blockIdx.y;
  const float* src = ((p == 0) ? Wq : (p == 1) ? Wk : Wv) + (size_t)h * E_ * D_;
  unsigned short* dst = wt + (size_t)(p * H_ + h) * D_ * E_;
  const int r0 = blockIdx.x * 64;  // e-tile
  const int lr = threadIdx.x >> 4, lc = (threadIdx.x & 15) * 4;
#pragma unroll
  for (int it = 0; it < 4; it++) {
    const float4 f = *(const float4*)(src + (size_t)(r0 + lr + it * 16) * D_ + lc);
    ts[lr + it * 16][lc] = f.x; ts[lr + it * 16][lc + 1] = f.y;
    ts[lr + it * 16][lc + 2] = f.z; ts[lr + it * 16][lc + 3] = f.w;
  }
  __syncthreads();
#pragma unroll
  for (int it = 0; it < 4; it++) {
    const int dr = lr + it * 16;  // d
    ushort4 pk;
    pk.x = f2h(ts[lc + 0][dr]); pk.y = f2h(ts[lc + 1][dr]);
    pk.z = f2h(ts[lc + 2][dr]); pk.w = f2h(ts[lc + 3][dr]);
    *(ushort4*)(dst + (size_t)dr * E_ + r0 + lc) = pk;
  }
}

// ---------------------------------------------------------------------------
// Prep 2: Wo [e][j] fp32 -> wot [j][e] fp16. grid=(16,16).
// ---------------------------------------------------------------------------
__global__ __launch_bounds__(256) void tconv_wo(const float* __restrict__ Wo,
                                                unsigned short* __restrict__ wot) {
  __shared__ float ts[64][65];
  const int r0 = blockIdx.x * 64;  // e-tile
  const int c0 = blockIdx.y * 64;  // j-tile
  const int lr = threadIdx.x >> 4, lc = (threadIdx.x & 15) * 4;
#pragma unroll
  for (int it = 0; it < 4; it++) {
    const float4 f = *(const float4*)(Wo + (size_t)(r0 + lr + it * 16) * E_ + c0 + lc);
    ts[lr + it * 16][lc] = f.x; ts[lr + it * 16][lc + 1] = f.y;
    ts[lr + it * 16][lc + 2] = f.z; ts[lr + it * 16][lc + 3] = f.w;
  }
  __syncthreads();
#pragma unroll
  for (int it = 0; it < 4; it++) {
    const int dr = lr + it * 16;  // j within tile
    ushort4 pk;
    pk.x = f2h(ts[lc + 0][dr]); pk.y = f2h(ts[lc + 1][dr]);
    pk.z = f2h(ts[lc + 2][dr]); pk.w = f2h(ts[lc + 3][dr]);
    *(ushort4*)(wot + (size_t)(c0 + dr) * E_ + r0 + lc) = pk;
  }
}

// ---------------------------------------------------------------------------
// Kernel 1: QKV projections via MFMA, coalesced LDS staging.
// grid=(B*T/128, H, 3), block=256 (4 waves).
// ---------------------------------------------------------------------------
__global__ __launch_bounds__(256) void qkv_mfma(
    const unsigned short* __restrict__ xh, const unsigned short* __restrict__ wt,
    unsigned short* __restrict__ qo, unsigned short* __restrict__ ko,
    unsigned short* __restrict__ vo)
{
  __shared__ unsigned short xs[128 * LD_];   // [token][e]
  __shared__ unsigned short wsb[64 * LD_];   // [d][e]
  __shared__ unsigned short Cl[4][32 * 72];  // per-wave repack tile

  const int tid = threadIdx.x;
  const int w = tid >> 6, lane = tid & 63;
  const int m16 = lane & 15, quad = lane >> 4;
  const int h = blockIdx.y, p = blockIdx.z;
  const int n0 = blockIdx.x * 128;           // block token base
  const unsigned short* wb = wt + (size_t)(p * H_ + h) * D_ * E_;

  const int sr = tid >> 3;          // 0..31
  const int sc = (tid & 7) * 8;     // 0,8,...,56

  f32x4 acc[2][4];
#pragma unroll
  for (int rt = 0; rt < 2; rt++)
#pragma unroll
    for (int ct = 0; ct < 4; ct++) acc[rt][ct] = (f32x4){0.f, 0.f, 0.f, 0.f};

  for (int e0 = 0; e0 < E_; e0 += 64) {
    __syncthreads();
#pragma unroll
    for (int it = 0; it < 4; it++) {
      const int row = it * 32 + sr;
      *(uint4*)(xs + row * LD_ + sc) =
          *(const uint4*)(xh + (size_t)(n0 + row) * E_ + e0 + sc);
    }
#pragma unroll
    for (int it = 0; it < 2; it++) {
      const int row = it * 32 + sr;
      *(uint4*)(wsb + row * LD_ + sc) =
          *(const uint4*)(wb + (size_t)row * E_ + e0 + sc);
    }
    __syncthreads();

#pragma unroll
    for (int kk = 0; kk < 64; kk += 32) {
      U4 a0, a1, bf[4];
      a0.u = *(const uint4*)(xs + (w * 32 + m16) * LD_ + kk + quad * 8);
      a1.u = *(const uint4*)(xs + (w * 32 + 16 + m16) * LD_ + kk + quad * 8);
#pragma unroll
      for (int ct = 0; ct < 4; ct++)
        bf[ct].u = *(const uint4*)(wsb + (ct * 16 + m16) * LD_ + kk + quad * 8);
#pragma unroll
      for (int ct = 0; ct < 4; ct++) {
        acc[0][ct] = __builtin_amdgcn_mfma_f32_16x16x32_f16(a0.h, bf[ct].h, acc[0][ct], 0, 0, 0);
        acc[1][ct] = __builtin_amdgcn_mfma_f32_16x16x32_f16(a1.h, bf[ct].h, acc[1][ct], 0, 0, 0);
      }
    }
  }

  const int nw = n0 + w * 32;               // wave token base
  const int b  = n0 >> 11;                  // batch (128 | 2048, never straddles)
  const int t0 = nw & (T_ - 1);
  const size_t bh = (size_t)(b * H_ + h);

  if (p == 2) {
#pragma unroll
    for (int rt = 0; rt < 2; rt++)
#pragma unroll
      for (int ct = 0; ct < 4; ct++) {
        const int d = ct * 16 + m16;
        const int t = t0 + rt * 16 + quad * 4;
        ushort4 pk;
        pk.x = f2h(acc[rt][ct][0]); pk.y = f2h(acc[rt][ct][1]);
        pk.z = f2h(acc[rt][ct][2]); pk.w = f2h(acc[rt][ct][3]);
        *(ushort4*)(vo + (bh * D_ + d) * (size_t)VTS_ + t) = pk;
      }
  } else {
    unsigned short* outp = (p == 0) ? qo : ko;
    unsigned short* Cw = &Cl[w][0];
#pragma unroll
    for (int rt = 0; rt < 2; rt++)
#pragma unroll
      for (int ct = 0; ct < 4; ct++)
#pragma unroll
        for (int r = 0; r < 4; r++)
          Cw[(rt * 16 + quad * 4 + r) * 72 + ct * 16 + m16] = f2h(acc[rt][ct][r]);
    const int row = lane >> 1;
    const int half = (lane & 1) * 32;
    const uint4 d0 = *(const uint4*)(Cw + row * 72 + half);
    const uint4 d1 = *(const uint4*)(Cw + row * 72 + half + 8);
    const uint4 d2 = *(const uint4*)(Cw + row * 72 + half + 16);
    const uint4 d3 = *(const uint4*)(Cw + row * 72 + half + 24);
    unsigned short* dst = outp + (bh * T_ + t0 + row) * D_ + half;
    *(uint4*)(dst)      = d0;
    *(uint4*)(dst + 8)  = d1;
    *(uint4*)(dst + 16) = d2;
    *(uint4*)(dst + 24) = d3;
  }
}

// ---------------------------------------------------------------------------
// Kernel 2: MFMA flash attention (round-14).
// grid = 1024 (flat, XCD-swizzled), block=256 (4 waves = 4 Q-tiles of 16).
//
// KVBLK=128, single LDS buffer (K[128][72] + V[64][144] = 36.9KB -> 4 blk/CU).
// Per tile: prefetch K (issue at top) and V (issue after QK) into regs;
// compute from LDS; barrier; write regs->LDS; barrier.  Softmax in-register
// via swapped QK^T; defer-max skips O-rescale when __all(ml - mrow <= 8).
// Accumulator o[4]: STATIC indices only (r12 spill lesson).
// ---------------------------------------------------------------------------
__global__ __launch_bounds__(256) void attn_kernel(
    const unsigned short* __restrict__ q, const unsigned short* __restrict__ k,
    const unsigned short* __restrict__ vt, unsigned short* __restrict__ comb)
{
  __shared__ unsigned short Kt[KV_ * LDK_];   // [key][d]   18432 B
  __shared__ unsigned short Vt[D_ * LDV_];    // [d][key]   18432 B

  const int tid  = threadIdx.x;
  const int w    = tid >> 6;
  const int lane = tid & 63;
  const int m16  = lane & 15;
  const int quad = lane >> 4;

  // XCD-bijective swizzle: XCD i (= flat%8) serves swz in [i*128, i*128+128)
  // = 4 whole (b,h) groups -> K/V (2MB) + Q (1MB) fit that XCD's 4MB L2.
  const int flat = blockIdx.x;                   // 0..1023
  const int swz  = (flat & 7) * 128 + (flat >> 3);
  const int xq   = swz & 31;
  const int h    = (swz >> 5) & 15;
  const int b    = swz >> 9;

  const size_t bh = (size_t)(b * H_ + h);
  const int q0 = xq * 64 + w * 16;

  // Q fragments; 1/sqrt(D)=0.125 folded in (exact power-of-2 scale in fp16).
  U4 aQ0, aQ1;
  {
    const unsigned short* qrow = q + (bh * T_ + q0 + m16) * (size_t)D_;
    aQ0.u = *(const uint4*)(qrow + quad * 8);
    aQ1.u = *(const uint4*)(qrow + 32 + quad * 8);
    aQ0.h = aQ0.h * (_Float16)0.125f;
    aQ1.h = aQ1.h * (_Float16)0.125f;
  }

  f32x4 o[4];
#pragma unroll
  for (int i = 0; i < 4; i++) o[i] = (f32x4){0.f, 0.f, 0.f, 0.f};
  float mrow = -1e30f;   // running max of q-row m16 (replicated across quads)
  float lrow = 0.f;      // running denom of q-row m16

  // staging geometry: K tile 128x64 (32 rows x 8 lanes/row per round, 4 rounds)
  //                   V tile 64x128 (16 rows x 16 lanes/row per round, 4 rounds)
  const int sr = tid >> 3, sc = (tid & 7) * 8;
  const int vr2 = tid >> 4, vc = (tid & 15) * 8;

  const unsigned short* kp = k  + bh * (size_t)(T_ * D_)   + sr * D_ + sc;
  const unsigned short* vp = vt + bh * (size_t)(D_ * VTS_) + vr2 * VTS_ + vc;
  unsigned short* ksw = Kt + sr * LDK_ + sc;
  unsigned short* vsw = Vt + vr2 * LDV_ + vc;

  uint4 krg[4], vrg[4];
  // prologue: stage tile 0
#pragma unroll
  for (int i = 0; i < 4; i++) krg[i] = *(const uint4*)(kp + i * 32 * D_);
#pragma unroll
  for (int i = 0; i < 4; i++) vrg[i] = *(const uint4*)(vp + i * 16 * VTS_);
  kp += KV_ * D_; vp += KV_;
#pragma unroll
  for (int i = 0; i < 4; i++) *(uint4*)(ksw + i * 32 * LDK_) = krg[i];
#pragma unroll
  for (int i = 0; i < 4; i++) *(uint4*)(vsw + i * 16 * LDV_) = vrg[i];
  __syncthreads();

  const unsigned short* Kw = Kt + m16 * LDK_ + quad * 8;
  const unsigned short* Vw = Vt + m16 * LDV_ + quad * 4;

  for (int t = 0; t < NTILE_; t++) {
    const bool more = (t + 1 < NTILE_);
    if (more) {
#pragma unroll
      for (int i = 0; i < 4; i++) krg[i] = *(const uint4*)(kp + i * 32 * D_);
      kp += KV_ * D_;
    }

    // QK^T swapped: st[ct][r] = S[q=m16][key = ct*16 + quad*4 + r] (scaled)
    f32x4 st[8];
#pragma unroll
    for (int ct = 0; ct < 8; ct++) {
      U4 kf0, kf1;
      kf0.u = *(const uint4*)(Kw + ct * 16 * LDK_);
      kf1.u = *(const uint4*)(Kw + ct * 16 * LDK_ + 32);
      f32x4 z = {0.f, 0.f, 0.f, 0.f};
      z = __builtin_amdgcn_mfma_f32_16x16x32_f16(kf0.h, aQ0.h, z, 0, 0, 0);
      z = __builtin_amdgcn_mfma_f32_16x16x32_f16(kf1.h, aQ1.h, z, 0, 0, 0);
      st[ct] = z;
    }

    if (more) {   // V prefetch issued here: softmax + PV cover the latency
#pragma unroll
      for (int i = 0; i < 4; i++) vrg[i] = *(const uint4*)(vp + i * 16 * VTS_);
      vp += KV_;
    }

    // row max: lane-local tree over 32 keys, then across quads
    float ml = fmaxf(fmaxf(st[0][0], st[0][1]), fmaxf(st[0][2], st[0][3]));
#pragma unroll
    for (int ct = 1; ct < 8; ct++) {
      const float mc = fmaxf(fmaxf(st[ct][0], st[ct][1]), fmaxf(st[ct][2], st[ct][3]));
      ml = fmaxf(ml, mc);
    }
    ml = fmaxf(ml, __shfl_xor(ml, 16));
    ml = fmaxf(ml, __shfl_xor(ml, 32));

    // defer-max: only rescale when some row grew by > 8 (P bounded by e^8)
    if (!__all(ml - mrow <= 8.0f)) {
      const float mn = fmaxf(mrow, ml);
      const float a  = __expf(mrow - mn);
      float al[4];
#pragma unroll
      for (int r = 0; r < 4; r++) al[r] = __shfl(a, quad * 4 + r);
#pragma unroll
      for (int i = 0; i < 4; i++)
#pragma unroll
        for (int r = 0; r < 4; r++) o[i][r] *= al[r];
      lrow *= a;
      mrow = mn;
    }
    const float mn = mrow;

    // exp + row sum; packed values directly form PV A-fragments
    float sl = 0.f;
    h4 pf[8];
#pragma unroll
    for (int ct = 0; ct < 8; ct++) {
      const float e0 = __expf(st[ct][0] - mn);
      const float e1 = __expf(st[ct][1] - mn);
      const float e2 = __expf(st[ct][2] - mn);
      const float e3 = __expf(st[ct][3] - mn);
      sl += (e0 + e1) + (e2 + e3);
      PK4 u;
      u.p[0] = __builtin_amdgcn_cvt_pkrtz(e0, e1);
      u.p[1] = __builtin_amdgcn_cvt_pkrtz(e2, e3);
      pf[ct] = u.h;
    }
    sl += __shfl_xor(sl, 16);
    sl += __shfl_xor(sl, 32);
    lrow += sl;

    // PV: 16x16x16 MFMAs; B-frag is a b64 LDS read; static acc indices only
#pragma unroll
    for (int ctd = 0; ctd < 4; ctd++) {
      const unsigned short* vrow = Vw + ctd * 16 * LDV_;
#pragma unroll
      for (int ctk = 0; ctk < 8; ctk++) {
        const h4 vf = *(const h4*)(vrow + ctk * 16);
        o[ctd] = __builtin_amdgcn_mfma_f32_16x16x16f16(pf[ctk], vf, o[ctd], 0, 0, 0);
      }
    }

    __syncthreads();   // all waves done reading Kt/Vt for tile t
    if (more) {
#pragma unroll
      for (int i = 0; i < 4; i++) *(uint4*)(ksw + i * 32 * LDK_) = krg[i];
#pragma unroll
      for (int i = 0; i < 4; i++) *(uint4*)(vsw + i * 16 * LDV_) = vrg[i];
      __syncthreads();  // writes visible before compute(t+1)
    }
  }

  float linv[4];
#pragma unroll
  for (int r = 0; r < 4; r++) linv[r] = 1.f / __shfl(lrow, quad * 4 + r);

#pragma unroll
  for (int r = 0; r < 4; r++) {
    const int tq = q0 + quad * 4 + r;
    unsigned short* dst = comb + ((size_t)b * T_ + tq) * E_ + h * D_;
    dst[m16]      = f2h(o[0][r] * linv[r]);
    dst[16 + m16] = f2h(o[1][r] * linv[r]);
    dst[32 + m16] = f2h(o[2][r] * linv[r]);
    dst[48 + m16] = f2h(o[3][r] * linv[r]);
  }
}

// ---------------------------------------------------------------------------
// Kernel 3: out = comb @ Wo + x, coalesced LDS staging.
// grid=(B*T/128, E/64), block=256 (4 waves). Block: 128 n x 64 j.
// ---------------------------------------------------------------------------
__global__ __launch_bounds__(256) void out_mfma(
    const unsigned short* __restrict__ comb, const unsigned short* __restrict__ wot,
    const float* __restrict__ x, float* __restrict__ out)
{
  __shared__ unsigned short cs[128 * LD_];   // [n][e]
  __shared__ unsigned short wsb[64 * LD_];   // [j][e]

  const int tid = threadIdx.x;
  const int w = tid >> 6, lane = tid & 63;
  const int m16 = lane & 15, quad = lane >> 4;
  const int n0 = blockIdx.x * 128;
  const int j0 = blockIdx.y * 64;

  const int sr = tid >> 3;          // 0..31
  const int sc = (tid & 7) * 8;     // 0,8,...,56

  f32x4 acc[2][4];
#pragma unroll
  for (int rt = 0; rt < 2; rt++)
#pragma unroll
    for (int ct = 0; ct < 4; ct++) acc[rt][ct] = (f32x4){0.f, 0.f, 0.f, 0.f};

  for (int e0 = 0; e0 < E_; e0 += 64) {
    __syncthreads();
#pragma unroll
    for (int it = 0; it < 4; it++) {
      const int row = it * 32 + sr;
      *(uint4*)(cs + row * LD_ + sc) =
          *(const uint4*)(comb + (size_t)(n0 + row) * E_ + e0 + sc);
    }
#pragma unroll
    for (int it = 0; it < 2; it++) {
      const int row = it * 32 + sr;
      *(uint4*)(wsb + row * LD_ + sc) =
          *(const uint4*)(wot + (size_t)(j0 + row) * E_ + e0 + sc);
    }
    __syncthreads();

#pragma unroll
    for (int kk = 0; kk < 64; kk += 32) {
      U4 a0, a1, bf[4];
      a0.u = *(const uint4*)(cs + (w * 32 + m16) * LD_ + kk + quad * 8);
      a1.u = *(const uint4*)(cs + (w * 32 + 16 + m16) * LD_ + kk + quad * 8);
#pragma unroll
      for (int ct = 0; ct < 4; ct++)
        bf[ct].u = *(const uint4*)(wsb + (ct * 16 + m16) * LD_ + kk + quad * 8);
#pragma unroll
      for (int ct = 0; ct < 4; ct++) {
        acc[0][ct] = __builtin_amdgcn_mfma_f32_16x16x32_f16(a0.h, bf[ct].h, acc[0][ct], 0, 0, 0);
        acc[1][ct] = __builtin_amdgcn_mfma_f32_16x16x32_f16(a1.h, bf[ct].h, acc[1][ct], 0, 0, 0);
      }
    }
  }

  const int nw = n0 + w * 32;
#pragma unroll
  for (int rt = 0; rt < 2; rt++)
#pragma unroll
    for (int r = 0; r < 4; r++) {
      const int n = nw + rt * 16 + quad * 4 + r;
      const float* xr = x + (size_t)n * E_ + j0;
      float* orow = out + (size_t)n * E_ + j0;
#pragma unroll
      for (int ct = 0; ct < 4; ct++) {
        const int j = ct * 16 + m16;
        orow[j] = acc[rt][ct][r] + xr[j];
      }
    }
}

// ---------------------------------------------------------------------------
extern "C" void kernel_launch(void* const* d_in, const int* in_sizes, int n_in,
                              void* d_out, int out_size, void* d_ws, size_t ws_size,
                              hipStream_t stream) {
  (void)in_sizes; (void)n_in; (void)out_size; (void)ws_size;

  const float* x  = (const float*)d_in[0];
  const float* Wq = (const float*)d_in[1];
  const float* Wk = (const float*)d_in[2];
  const float* Wv = (const float*)d_in[3];
  const float* Wo = (const float*)d_in[4];
  float* out = (float*)d_out;

  unsigned short* ws0  = (unsigned short*)d_ws;
  unsigned short* xh   = ws0;                    // 4M elems (aliases comb)
  unsigned short* wt   = ws0 + 4194304;          // 3M
  unsigned short* wot  = ws0 + 7340032;          // 1M
  unsigned short* qh   = ws0 + 8388608;          // 4M
  unsigned short* kh   = ws0 + 12582912;         // 4M
  unsigned short* vth  = ws0 + 16777216;         // 32*64*2176 = 4.46M (padded)
  unsigned short* comb = xh;                     // alias: xh dead after qkv

  cvt_x<<<dim3(B_ * T_ * E_ / 1024), dim3(256), 0, stream>>>(x, xh);
  tconv_w<<<dim3(E_ / 64, H_, 3), dim3(256), 0, stream>>>(Wq, Wk, Wv, wt);
  tconv_wo<<<dim3(E_ / 64, E_ / 64), dim3(256), 0, stream>>>(Wo, wot);

  qkv_mfma<<<dim3(B_ * T_ / 128, H_, 3), dim3(256), 0, stream>>>(xh, wt, qh, kh, vth);

  attn_kernel<<<dim3(B_ * H_ * (T_ / 64)), dim3(256), 0, stream>>>(qh, kh, vth, comb);

  out_mfma<<<dim3(B_ * T_ / 128, E_ / 64), dim3(256), 0, stream>>>(comb, wot, x, out);
}

// Round 5
// 221.403 us; speedup vs baseline: 1.3745x; 1.3745x over previous
//
#include <hip/hip_runtime.h>
#include <hip/hip_bf16.h>

// MultiAttentionHead: B=2, T=2048, E=1024, H=16, D=64
// Inputs (fp32): x[B,T,E], Wq[H,E,D], Wk[H,E,D], Wv[H,E,D], Wo[E,E]
// Output (fp32): combined @ Wo + x   [B,T,E]
//
// ws layout (ushort=fp16 elements):
//   xh/comb : 0 .. 4M   wt : 4M .. 7.34M   wot : 7.34M .. 8.39M
//   q : 8.39M  k : 12.58M  vt : 16.78M .. 21.24M
//
// r10: GEMM fragment gathers stage through LDS with lane-contiguous loads.
// r11: attn softmax fully in-register (swapped QK^T -> S^T lane-local rows;
//      exp'd values are directly the 16x16x16 PV A-fragment). 90.3us attn.
// r12-r14: KV=128 attempt SPILLED (st[8]+krg/vrg+o+pf ~118 regs + MFMA
//      alignment -> allocator spilled st[] to scratch; WRITE_SIZE 8->525MB,
//      attn 169us). Static-index fix didn't help -> cause is total pressure,
//      not the pointer-select. LESSON: this attn structure must stay at
//      KV=64 register footprint (~90 regs).
// r15 (this round): revert to the proven r11 structure (KV=64, LDS double
//      buffer); add ONLY the two register-neutral wins never yet measured:
//      (a) XCD-bijective block swizzle (each XCD owns 4 (b,h) groups ->
//          K/V/Q ~3.1MB L2-resident per XCD),
//      (b) defer-max rescale (THR=8: skip O-rescale while row max grows
//          <= 8; P bounded by e^8, fp16-safe, f32 accum).

#define B_ 2
#define T_ 2048
#define E_ 1024
#define H_ 16
#define D_ 64
#define VTS_ 2176   // padded vt leading dim (elements)
#define LD_ 72      // LDS tile row stride (elements; 64 + 8, keeps 16B align)

typedef _Float16 h8 __attribute__((ext_vector_type(8)));
typedef _Float16 h4 __attribute__((ext_vector_type(4)));
typedef float f32x4 __attribute__((ext_vector_type(4)));

union U4 { uint4 u; h8 h; };

__device__ __forceinline__ float h2f(unsigned short s) {
  _Float16 h;
  __builtin_memcpy(&h, &s, 2);
  return (float)h;
}

__device__ __forceinline__ unsigned short f2h(float f) {
  _Float16 h = (_Float16)f;
  unsigned short s;
  __builtin_memcpy(&s, &h, 2);
  return s;
}

// ---------------------------------------------------------------------------
// Prep 0: x fp32 -> fp16.  grid = B*T*E/1024, block=256.
// ---------------------------------------------------------------------------
__global__ __launch_bounds__(256) void cvt_x(const float* __restrict__ x,
                                             unsigned short* __restrict__ xh) {
  const size_t i = ((size_t)blockIdx.x * 256 + threadIdx.x) * 4;
  const float4 f = *(const float4*)(x + i);
  ushort4 pk;
  pk.x = f2h(f.x); pk.y = f2h(f.y); pk.z = f2h(f.z); pk.w = f2h(f.w);
  *(ushort4*)(xh + i) = pk;
}

// ---------------------------------------------------------------------------
// Prep 1: Wq/Wk/Wv [h][e][d] fp32 -> wt [p][h][d][e] fp16. grid=(16,16,3).
// ---------------------------------------------------------------------------
__global__ __launch_bounds__(256) void tconv_w(
    const float* __restrict__ Wq, const float* __restrict__ Wk,
    const float* __restrict__ Wv, unsigned short* __restrict__ wt) {
  __shared__ float ts[64][65];
  const int p = blockIdx.z, h = blockIdx.y;
  const float* src = ((p == 0) ? Wq : (p == 1) ? Wk : Wv) + (size_t)h * E_ * D_;
  unsigned short* dst = wt + (size_t)(p * H_ + h) * D_ * E_;
  const int r0 = blockIdx.x * 64;  // e-tile
  const int lr = threadIdx.x >> 4, lc = (threadIdx.x & 15) * 4;
#pragma unroll
  for (int it = 0; it < 4; it++) {
    const float4 f = *(const float4*)(src + (size_t)(r0 + lr + it * 16) * D_ + lc);
    ts[lr + it * 16][lc] = f.x; ts[lr + it * 16][lc + 1] = f.y;
    ts[lr + it * 16][lc + 2] = f.z; ts[lr + it * 16][lc + 3] = f.w;
  }
  __syncthreads();
#pragma unroll
  for (int it = 0; it < 4; it++) {
    const int dr = lr + it * 16;  // d
    ushort4 pk;
    pk.x = f2h(ts[lc + 0][dr]); pk.y = f2h(ts[lc + 1][dr]);
    pk.z = f2h(ts[lc + 2][dr]); pk.w = f2h(ts[lc + 3][dr]);
    *(ushort4*)(dst + (size_t)dr * E_ + r0 + lc) = pk;
  }
}

// ---------------------------------------------------------------------------
// Prep 2: Wo [e][j] fp32 -> wot [j][e] fp16. grid=(16,16).
// ---------------------------------------------------------------------------
__global__ __launch_bounds__(256) void tconv_wo(const float* __restrict__ Wo,
                                                unsigned short* __restrict__ wot) {
  __shared__ float ts[64][65];
  const int r0 = blockIdx.x * 64;  // e-tile
  const int c0 = blockIdx.y * 64;  // j-tile
  const int lr = threadIdx.x >> 4, lc = (threadIdx.x & 15) * 4;
#pragma unroll
  for (int it = 0; it < 4; it++) {
    const float4 f = *(const float4*)(Wo + (size_t)(r0 + lr + it * 16) * E_ + c0 + lc);
    ts[lr + it * 16][lc] = f.x; ts[lr + it * 16][lc + 1] = f.y;
    ts[lr + it * 16][lc + 2] = f.z; ts[lr + it * 16][lc + 3] = f.w;
  }
  __syncthreads();
#pragma unroll
  for (int it = 0; it < 4; it++) {
    const int dr = lr + it * 16;  // j within tile
    ushort4 pk;
    pk.x = f2h(ts[lc + 0][dr]); pk.y = f2h(ts[lc + 1][dr]);
    pk.z = f2h(ts[lc + 2][dr]); pk.w = f2h(ts[lc + 3][dr]);
    *(ushort4*)(wot + (size_t)(c0 + dr) * E_ + r0 + lc) = pk;
  }
}

// ---------------------------------------------------------------------------
// Kernel 1: QKV projections via MFMA, coalesced LDS staging.
// grid=(B*T/128, H, 3), block=256 (4 waves).
// ---------------------------------------------------------------------------
__global__ __launch_bounds__(256) void qkv_mfma(
    const unsigned short* __restrict__ xh, const unsigned short* __restrict__ wt,
    unsigned short* __restrict__ qo, unsigned short* __restrict__ ko,
    unsigned short* __restrict__ vo)
{
  __shared__ unsigned short xs[128 * LD_];   // [token][e]
  __shared__ unsigned short wsb[64 * LD_];   // [d][e]
  __shared__ unsigned short Cl[4][32 * 72];  // per-wave repack tile

  const int tid = threadIdx.x;
  const int w = tid >> 6, lane = tid & 63;
  const int m16 = lane & 15, quad = lane >> 4;
  const int h = blockIdx.y, p = blockIdx.z;
  const int n0 = blockIdx.x * 128;           // block token base
  const unsigned short* wb = wt + (size_t)(p * H_ + h) * D_ * E_;

  const int sr = tid >> 3;          // 0..31
  const int sc = (tid & 7) * 8;     // 0,8,...,56

  f32x4 acc[2][4];
#pragma unroll
  for (int rt = 0; rt < 2; rt++)
#pragma unroll
    for (int ct = 0; ct < 4; ct++) acc[rt][ct] = (f32x4){0.f, 0.f, 0.f, 0.f};

  for (int e0 = 0; e0 < E_; e0 += 64) {
    __syncthreads();
#pragma unroll
    for (int it = 0; it < 4; it++) {
      const int row = it * 32 + sr;
      *(uint4*)(xs + row * LD_ + sc) =
          *(const uint4*)(xh + (size_t)(n0 + row) * E_ + e0 + sc);
    }
#pragma unroll
    for (int it = 0; it < 2; it++) {
      const int row = it * 32 + sr;
      *(uint4*)(wsb + row * LD_ + sc) =
          *(const uint4*)(wb + (size_t)row * E_ + e0 + sc);
    }
    __syncthreads();

#pragma unroll
    for (int kk = 0; kk < 64; kk += 32) {
      U4 a0, a1, bf[4];
      a0.u = *(const uint4*)(xs + (w * 32 + m16) * LD_ + kk + quad * 8);
      a1.u = *(const uint4*)(xs + (w * 32 + 16 + m16) * LD_ + kk + quad * 8);
#pragma unroll
      for (int ct = 0; ct < 4; ct++)
        bf[ct].u = *(const uint4*)(wsb + (ct * 16 + m16) * LD_ + kk + quad * 8);
#pragma unroll
      for (int ct = 0; ct < 4; ct++) {
        acc[0][ct] = __builtin_amdgcn_mfma_f32_16x16x32_f16(a0.h, bf[ct].h, acc[0][ct], 0, 0, 0);
        acc[1][ct] = __builtin_amdgcn_mfma_f32_16x16x32_f16(a1.h, bf[ct].h, acc[1][ct], 0, 0, 0);
      }
    }
  }

  const int nw = n0 + w * 32;               // wave token base
  const int b  = n0 >> 11;                  // batch (128 | 2048, never straddles)
  const int t0 = nw & (T_ - 1);
  const size_t bh = (size_t)(b * H_ + h);

  if (p == 2) {
#pragma unroll
    for (int rt = 0; rt < 2; rt++)
#pragma unroll
      for (int ct = 0; ct < 4; ct++) {
        const int d = ct * 16 + m16;
        const int t = t0 + rt * 16 + quad * 4;
        ushort4 pk;
        pk.x = f2h(acc[rt][ct][0]); pk.y = f2h(acc[rt][ct][1]);
        pk.z = f2h(acc[rt][ct][2]); pk.w = f2h(acc[rt][ct][3]);
        *(ushort4*)(vo + (bh * D_ + d) * (size_t)VTS_ + t) = pk;
      }
  } else {
    unsigned short* outp = (p == 0) ? qo : ko;
    unsigned short* Cw = &Cl[w][0];
#pragma unroll
    for (int rt = 0; rt < 2; rt++)
#pragma unroll
      for (int ct = 0; ct < 4; ct++)
#pragma unroll
        for (int r = 0; r < 4; r++)
          Cw[(rt * 16 + quad * 4 + r) * 72 + ct * 16 + m16] = f2h(acc[rt][ct][r]);
    const int row = lane >> 1;
    const int half = (lane & 1) * 32;
    const uint4 d0 = *(const uint4*)(Cw + row * 72 + half);
    const uint4 d1 = *(const uint4*)(Cw + row * 72 + half + 8);
    const uint4 d2 = *(const uint4*)(Cw + row * 72 + half + 16);
    const uint4 d3 = *(const uint4*)(Cw + row * 72 + half + 24);
    unsigned short* dst = outp + (bh * T_ + t0 + row) * D_ + half;
    *(uint4*)(dst)      = d0;
    *(uint4*)(dst + 8)  = d1;
    *(uint4*)(dst + 16) = d2;
    *(uint4*)(dst + 24) = d3;
  }
}

// ---------------------------------------------------------------------------
// Kernel 2: MFMA flash attention (round-15 = r11 structure + swizzle +
// defer-max).  grid = 1024 flat (XCD-swizzled), block=256 (4 waves = 4
// Q-tiles of 16 rows).  KV tile = 64, LDS double-buffered (36.9KB).
// ---------------------------------------------------------------------------
__global__ __launch_bounds__(256) void attn_kernel(
    const unsigned short* __restrict__ q, const unsigned short* __restrict__ k,
    const unsigned short* __restrict__ vt, unsigned short* __restrict__ comb)
{
  __shared__ unsigned short Kt[2][64 * LD_];   // [key][d]
  __shared__ unsigned short Vt[2][64 * LD_];   // [d][key]

  const int tid  = threadIdx.x;
  const int w    = tid >> 6;
  const int lane = tid & 63;
  const int m16  = lane & 15;
  const int quad = lane >> 4;

  // XCD-bijective swizzle: XCD i (= flat%8, dispatch round-robin) serves
  // swz in [i*128, (i+1)*128) = 4 whole (b,h) groups -> K/V/Q ~3.1MB fits
  // that XCD's 4MB L2.
  const int flat = blockIdx.x;                   // 0..1023
  const int swz  = (flat & 7) * 128 + (flat >> 3);
  const int xq   = swz & 31;
  const int h    = (swz >> 5) & 15;
  const int b    = swz >> 9;

  const size_t bh = (size_t)(b * H_ + h);
  const int q0 = xq * 64 + w * 16;

  // Q fragments; 1/sqrt(D)=0.125 folded in (exact power-of-2 scale in fp16).
  U4 aQ0, aQ1;
  {
    const unsigned short* qrow = q + (bh * T_ + q0 + m16) * (size_t)D_;
    aQ0.u = *(const uint4*)(qrow + quad * 8);
    aQ1.u = *(const uint4*)(qrow + 32 + quad * 8);
    aQ0.h = aQ0.h * (_Float16)0.125f;
    aQ1.h = aQ1.h * (_Float16)0.125f;
  }

  f32x4 o[4];
#pragma unroll
  for (int i = 0; i < 4; i++) o[i] = (f32x4){0.f, 0.f, 0.f, 0.f};
  float mrow = -1e30f;   // running max of q-row m16 (replicated across quads)
  float lrow = 0.f;      // running denom of q-row m16

  const unsigned short* kb  = k  + bh * (size_t)(T_ * D_);
  const unsigned short* vtb = vt + bh * (size_t)(D_ * VTS_);

  const int sr = tid >> 3;          // 0..31
  const int sc = (tid & 7) * 8;     // 0,8,...,56

  uint4 kr0, kr1, vr0, vr1;
  // prologue: stage tile 0
  kr0 = *(const uint4*)(kb + (size_t)sr * D_ + sc);
  kr1 = *(const uint4*)(kb + (size_t)(32 + sr) * D_ + sc);
  vr0 = *(const uint4*)(vtb + (size_t)sr * VTS_ + sc);
  vr1 = *(const uint4*)(vtb + (size_t)(32 + sr) * VTS_ + sc);
  *(uint4*)(&Kt[0][0] + sr * LD_ + sc)        = kr0;
  *(uint4*)(&Kt[0][0] + (32 + sr) * LD_ + sc) = kr1;
  *(uint4*)(&Vt[0][0] + sr * LD_ + sc)        = vr0;
  *(uint4*)(&Vt[0][0] + (32 + sr) * LD_ + sc) = vr1;
  __syncthreads();

  const int NT = T_ / 64;
  for (int t = 0; t < NT; t++) {
    const int cur = t & 1;
    const unsigned short* Kc = &Kt[cur][0];
    const unsigned short* Vc = &Vt[cur][0];
    const bool more = (t + 1 < NT);
    if (more) {
      const int kt = (t + 1) * 64;   // issue next tile a full compute early
      kr0 = *(const uint4*)(kb + (size_t)(kt + sr) * D_ + sc);
      kr1 = *(const uint4*)(kb + (size_t)(kt + 32 + sr) * D_ + sc);
      vr0 = *(const uint4*)(vtb + (size_t)sr * VTS_ + kt + sc);
      vr1 = *(const uint4*)(vtb + (size_t)(32 + sr) * VTS_ + kt + sc);
    }

    // QK^T swapped: st[ct][r] = S[q=m16][key = ct*16 + quad*4 + r] (scaled)
    f32x4 st[4];
#pragma unroll
    for (int ct = 0; ct < 4; ct++) {
      U4 kf0, kf1;
      kf0.u = *(const uint4*)(Kc + (ct * 16 + m16) * LD_ + quad * 8);
      kf1.u = *(const uint4*)(Kc + (ct * 16 + m16) * LD_ + 32 + quad * 8);
      f32x4 z = {0.f, 0.f, 0.f, 0.f};
      z = __builtin_amdgcn_mfma_f32_16x16x32_f16(kf0.h, aQ0.h, z, 0, 0, 0);
      z = __builtin_amdgcn_mfma_f32_16x16x32_f16(kf1.h, aQ1.h, z, 0, 0, 0);
      st[ct] = z;
    }

    // row max: lane-local tree over 16 keys, then combine across quads
    const float m0 = fmaxf(fmaxf(st[0][0], st[0][1]), fmaxf(st[0][2], st[0][3]));
    const float m1 = fmaxf(fmaxf(st[1][0], st[1][1]), fmaxf(st[1][2], st[1][3]));
    const float m2 = fmaxf(fmaxf(st[2][0], st[2][1]), fmaxf(st[2][2], st[2][3]));
    const float m3 = fmaxf(fmaxf(st[3][0], st[3][1]), fmaxf(st[3][2], st[3][3]));
    float ml = fmaxf(fmaxf(m0, m1), fmaxf(m2, m3));
    ml = fmaxf(ml, __shfl_xor(ml, 16));
    ml = fmaxf(ml, __shfl_xor(ml, 32));

    // defer-max: rescale only when some row's max grew by > 8 (P <= e^8)
    if (!__all(ml - mrow <= 8.0f)) {
      const float mn2 = fmaxf(mrow, ml);
      const float a   = __expf(mrow - mn2);
      float al[4];
#pragma unroll
      for (int r = 0; r < 4; r++) al[r] = __shfl(a, quad * 4 + r);
#pragma unroll
      for (int i = 0; i < 4; i++)
#pragma unroll
        for (int r = 0; r < 4; r++) o[i][r] *= al[r];
      lrow *= a;
      mrow = mn2;
    }
    const float mn = mrow;

    // exp + row sum; packed values directly form PV A-fragments
    float sl = 0.f;
    h4 pf[4];
#pragma unroll
    for (int ct = 0; ct < 4; ct++) {
      const float e0 = __expf(st[ct][0] - mn);
      const float e1 = __expf(st[ct][1] - mn);
      const float e2 = __expf(st[ct][2] - mn);
      const float e3 = __expf(st[ct][3] - mn);
      sl += (e0 + e1) + (e2 + e3);
      pf[ct] = (h4){(_Float16)e0, (_Float16)e1, (_Float16)e2, (_Float16)e3};
    }
    sl += __shfl_xor(sl, 16);
    sl += __shfl_xor(sl, 32);
    lrow += sl;

    // PV: 16x16x16 MFMAs; B-frag is a b64 LDS read (2-way bank alias = free)
#pragma unroll
    for (int ctd = 0; ctd < 4; ctd++) {
      const unsigned short* vrow = Vc + (ctd * 16 + m16) * LD_ + quad * 4;
#pragma unroll
      for (int ctk = 0; ctk < 4; ctk++) {
        const h4 vf = *(const h4*)(vrow + ctk * 16);
        o[ctd] = __builtin_amdgcn_mfma_f32_16x16x16f16(pf[ctk], vf, o[ctd], 0, 0, 0);
      }
    }

    if (more) {
      __syncthreads();   // all waves done reading buf[cur^1] (tile t-1)
      unsigned short* Kn = &Kt[cur ^ 1][0];
      unsigned short* Vn = &Vt[cur ^ 1][0];
      *(uint4*)(Kn + sr * LD_ + sc)        = kr0;
      *(uint4*)(Kn + (32 + sr) * LD_ + sc) = kr1;
      *(uint4*)(Vn + sr * LD_ + sc)        = vr0;
      *(uint4*)(Vn + (32 + sr) * LD_ + sc) = vr1;
      __syncthreads();   // writes visible before compute(t+1)
    }
  }

  float linv[4];
#pragma unroll
  for (int r = 0; r < 4; r++) linv[r] = 1.f / __shfl(lrow, quad * 4 + r);

#pragma unroll
  for (int r = 0; r < 4; r++) {
    const int tq = q0 + quad * 4 + r;
    unsigned short* dst = comb + ((size_t)b * T_ + tq) * E_ + h * D_;
    dst[m16]      = f2h(o[0][r] * linv[r]);
    dst[16 + m16] = f2h(o[1][r] * linv[r]);
    dst[32 + m16] = f2h(o[2][r] * linv[r]);
    dst[48 + m16] = f2h(o[3][r] * linv[r]);
  }
}

// ---------------------------------------------------------------------------
// Kernel 3: out = comb @ Wo + x, coalesced LDS staging.
// grid=(B*T/128, E/64), block=256 (4 waves). Block: 128 n x 64 j.
// ---------------------------------------------------------------------------
__global__ __launch_bounds__(256) void out_mfma(
    const unsigned short* __restrict__ comb, const unsigned short* __restrict__ wot,
    const float* __restrict__ x, float* __restrict__ out)
{
  __shared__ unsigned short cs[128 * LD_];   // [n][e]
  __shared__ unsigned short wsb[64 * LD_];   // [j][e]

  const int tid = threadIdx.x;
  const int w = tid >> 6, lane = tid & 63;
  const int m16 = lane & 15, quad = lane >> 4;
  const int n0 = blockIdx.x * 128;
  const int j0 = blockIdx.y * 64;

  const int sr = tid >> 3;          // 0..31
  const int sc = (tid & 7) * 8;     // 0,8,...,56

  f32x4 acc[2][4];
#pragma unroll
  for (int rt = 0; rt < 2; rt++)
#pragma unroll
    for (int ct = 0; ct < 4; ct++) acc[rt][ct] = (f32x4){0.f, 0.f, 0.f, 0.f};

  for (int e0 = 0; e0 < E_; e0 += 64) {
    __syncthreads();
#pragma unroll
    for (int it = 0; it < 4; it++) {
      const int row = it * 32 + sr;
      *(uint4*)(cs + row * LD_ + sc) =
          *(const uint4*)(comb + (size_t)(n0 + row) * E_ + e0 + sc);
    }
#pragma unroll
    for (int it = 0; it < 2; it++) {
      const int row = it * 32 + sr;
      *(uint4*)(wsb + row * LD_ + sc) =
          *(const uint4*)(wot + (size_t)(j0 + row) * E_ + e0 + sc);
    }
    __syncthreads();

#pragma unroll
    for (int kk = 0; kk < 64; kk += 32) {
      U4 a0, a1, bf[4];
      a0.u = *(const uint4*)(cs + (w * 32 + m16) * LD_ + kk + quad * 8);
      a1.u = *(const uint4*)(cs + (w * 32 + 16 + m16) * LD_ + kk + quad * 8);
#pragma unroll
      for (int ct = 0; ct < 4; ct++)
        bf[ct].u = *(const uint4*)(wsb + (ct * 16 + m16) * LD_ + kk + quad * 8);
#pragma unroll
      for (int ct = 0; ct < 4; ct++) {
        acc[0][ct] = __builtin_amdgcn_mfma_f32_16x16x32_f16(a0.h, bf[ct].h, acc[0][ct], 0, 0, 0);
        acc[1][ct] = __builtin_amdgcn_mfma_f32_16x16x32_f16(a1.h, bf[ct].h, acc[1][ct], 0, 0, 0);
      }
    }
  }

  const int nw = n0 + w * 32;
#pragma unroll
  for (int rt = 0; rt < 2; rt++)
#pragma unroll
    for (int r = 0; r < 4; r++) {
      const int n = nw + rt * 16 + quad * 4 + r;
      const float* xr = x + (size_t)n * E_ + j0;
      float* orow = out + (size_t)n * E_ + j0;
#pragma unroll
      for (int ct = 0; ct < 4; ct++) {
        const int j = ct * 16 + m16;
        orow[j] = acc[rt][ct][r] + xr[j];
      }
    }
}

// ---------------------------------------------------------------------------
extern "C" void kernel_launch(void* const* d_in, const int* in_sizes, int n_in,
                              void* d_out, int out_size, void* d_ws, size_t ws_size,
                              hipStream_t stream) {
  (void)in_sizes; (void)n_in; (void)out_size; (void)ws_size;

  const float* x  = (const float*)d_in[0];
  const float* Wq = (const float*)d_in[1];
  const float* Wk = (const float*)d_in[2];
  const float* Wv = (const float*)d_in[3];
  const float* Wo = (const float*)d_in[4];
  float* out = (float*)d_out;

  unsigned short* ws0  = (unsigned short*)d_ws;
  unsigned short* xh   = ws0;                    // 4M elems (aliases comb)
  unsigned short* wt   = ws0 + 4194304;          // 3M
  unsigned short* wot  = ws0 + 7340032;          // 1M
  unsigned short* qh   = ws0 + 8388608;          // 4M
  unsigned short* kh   = ws0 + 12582912;         // 4M
  unsigned short* vth  = ws0 + 16777216;         // 32*64*2176 = 4.46M (padded)
  unsigned short* comb = xh;                     // alias: xh dead after qkv

  cvt_x<<<dim3(B_ * T_ * E_ / 1024), dim3(256), 0, stream>>>(x, xh);
  tconv_w<<<dim3(E_ / 64, H_, 3), dim3(256), 0, stream>>>(Wq, Wk, Wv, wt);
  tconv_wo<<<dim3(E_ / 64, E_ / 64), dim3(256), 0, stream>>>(Wo, wot);

  qkv_mfma<<<dim3(B_ * T_ / 128, H_, 3), dim3(256), 0, stream>>>(xh, wt, qh, kh, vth);

  attn_kernel<<<dim3(B_ * H_ * (T_ / 64)), dim3(256), 0, stream>>>(qh, kh, vth, comb);

  out_mfma<<<dim3(B_ * T_ / 128, E_ / 64), dim3(256), 0, stream>>>(comb, wot, x, out);
}

// Round 7
// 206.267 us; speedup vs baseline: 1.4753x; 1.0734x over previous
//
#include <hip/hip_runtime.h>
#include <hip/hip_bf16.h>

// MultiAttentionHead: B=2, T=2048, E=1024, H=16, D=64
// Inputs (fp32): x[B,T,E], Wq[H,E,D], Wk[H,E,D], Wv[H,E,D], Wo[E,E]
// Output (fp32): combined @ Wo + x   [B,T,E]
//
// r10: GEMM fragment gathers stage through LDS with lane-contiguous loads.
// r11: attn softmax fully in-register (swapped QK^T -> S^T lane-local rows;
//      exp'd values are directly the 16x16x16 PV A-fragment). 90.3us attn.
// r12-r14: KV=128 SPILLED (register pressure). LESSON: per-wave live state
//      must stay at the KV=64 footprint (~90 regs).
// r15: XCD-bijective swizzle -> FETCH 70->12MB (K/V/Q L2-resident, HBM 3%);
//      defer-max. 86.2us attn. Execution-bound: VALU 53-55%, Mfma 24-25%,
//      bank conflicts 12.58M.
// r16: 8-wave blocks + permuted V + exp2 softmax -> NaN. BUG: V16 union had
//      h4 f[4] (32B) over uint4 (16B); f[2]/f[3] were uninitialized garbage
//      into PV MFMA. 16 permuted ELEMENTS = TWO b128 reads, not one.
// r17 (this round): same structure, correct read: two uint4 per ctd
//      (V8 union, h4 f[2]); PV = 8x b128, conflict-free by bank analysis.

#define B_ 2
#define T_ 2048
#define E_ 1024
#define H_ 16
#define D_ 64
#define VTS_ 2176   // padded vt leading dim (elements)
#define LD_ 72      // LDS tile row stride (elements; 64 + 8, keeps 16B align)

typedef _Float16 h8 __attribute__((ext_vector_type(8)));
typedef _Float16 h4 __attribute__((ext_vector_type(4)));
typedef float f32x4 __attribute__((ext_vector_type(4)));

union U4 { uint4 u; h8 h; };
union V8 { uint4 u; h4 f[2]; };   // 16 bytes = 8 halves = 2 PV B-fragments

__device__ __forceinline__ float h2f(unsigned short s) {
  _Float16 h;
  __builtin_memcpy(&h, &s, 2);
  return (float)h;
}

__device__ __forceinline__ unsigned short f2h(float f) {
  _Float16 h = (_Float16)f;
  unsigned short s;
  __builtin_memcpy(&s, &h, 2);
  return s;
}

// exp2 via v_exp_f32 when available; mathematically-identical fallback.
__device__ __forceinline__ float fexp2(float x) {
#if __has_builtin(__builtin_amdgcn_exp2f)
  return __builtin_amdgcn_exp2f(x);
#else
  return __expf(x * 0.6931471805599453f);
#endif
}

// ---------------------------------------------------------------------------
// Prep 0: x fp32 -> fp16.  grid = B*T*E/1024, block=256.
// ---------------------------------------------------------------------------
__global__ __launch_bounds__(256) void cvt_x(const float* __restrict__ x,
                                             unsigned short* __restrict__ xh) {
  const size_t i = ((size_t)blockIdx.x * 256 + threadIdx.x) * 4;
  const float4 f = *(const float4*)(x + i);
  ushort4 pk;
  pk.x = f2h(f.x); pk.y = f2h(f.y); pk.z = f2h(f.z); pk.w = f2h(f.w);
  *(ushort4*)(xh + i) = pk;
}

// ---------------------------------------------------------------------------
// Prep 1: Wq/Wk/Wv [h][e][d] fp32 -> wt [p][h][d][e] fp16. grid=(16,16,3).
// Wq additionally scaled by 0.125*log2e (softmax runs in exp2 domain).
// ---------------------------------------------------------------------------
__global__ __launch_bounds__(256) void tconv_w(
    const float* __restrict__ Wq, const float* __restrict__ Wk,
    const float* __restrict__ Wv, unsigned short* __restrict__ wt) {
  __shared__ float ts[64][65];
  const int p = blockIdx.z, h = blockIdx.y;
  const float* src = ((p == 0) ? Wq : (p == 1) ? Wk : Wv) + (size_t)h * E_ * D_;
  unsigned short* dst = wt + (size_t)(p * H_ + h) * D_ * E_;
  const float scl = (p == 0) ? 0.18033688011112042f : 1.0f;  // 0.125*log2(e)
  const int r0 = blockIdx.x * 64;  // e-tile
  const int lr = threadIdx.x >> 4, lc = (threadIdx.x & 15) * 4;
#pragma unroll
  for (int it = 0; it < 4; it++) {
    const float4 f = *(const float4*)(src + (size_t)(r0 + lr + it * 16) * D_ + lc);
    ts[lr + it * 16][lc] = f.x * scl; ts[lr + it * 16][lc + 1] = f.y * scl;
    ts[lr + it * 16][lc + 2] = f.z * scl; ts[lr + it * 16][lc + 3] = f.w * scl;
  }
  __syncthreads();
#pragma unroll
  for (int it = 0; it < 4; it++) {
    const int dr = lr + it * 16;  // d
    ushort4 pk;
    pk.x = f2h(ts[lc + 0][dr]); pk.y = f2h(ts[lc + 1][dr]);
    pk.z = f2h(ts[lc + 2][dr]); pk.w = f2h(ts[lc + 3][dr]);
    *(ushort4*)(dst + (size_t)dr * E_ + r0 + lc) = pk;
  }
}

// ---------------------------------------------------------------------------
// Prep 2: Wo [e][j] fp32 -> wot [j][e] fp16. grid=(16,16).
// ---------------------------------------------------------------------------
__global__ __launch_bounds__(256) void tconv_wo(const float* __restrict__ Wo,
                                                unsigned short* __restrict__ wot) {
  __shared__ float ts[64][65];
  const int r0 = blockIdx.x * 64;  // e-tile
  const int c0 = blockIdx.y * 64;  // j-tile
  const int lr = threadIdx.x >> 4, lc = (threadIdx.x & 15) * 4;
#pragma unroll
  for (int it = 0; it < 4; it++) {
    const float4 f = *(const float4*)(Wo + (size_t)(r0 + lr + it * 16) * E_ + c0 + lc);
    ts[lr + it * 16][lc] = f.x; ts[lr + it * 16][lc + 1] = f.y;
    ts[lr + it * 16][lc + 2] = f.z; ts[lr + it * 16][lc + 3] = f.w;
  }
  __syncthreads();
#pragma unroll
  for (int it = 0; it < 4; it++) {
    const int dr = lr + it * 16;  // j within tile
    ushort4 pk;
    pk.x = f2h(ts[lc + 0][dr]); pk.y = f2h(ts[lc + 1][dr]);
    pk.z = f2h(ts[lc + 2][dr]); pk.w = f2h(ts[lc + 3][dr]);
    *(ushort4*)(wot + (size_t)(c0 + dr) * E_ + r0 + lc) = pk;
  }
}

// ---------------------------------------------------------------------------
// Kernel 1: QKV projections via MFMA, coalesced LDS staging.
// grid=(B*T/128, H, 3), block=256 (4 waves).
// ---------------------------------------------------------------------------
__global__ __launch_bounds__(256) void qkv_mfma(
    const unsigned short* __restrict__ xh, const unsigned short* __restrict__ wt,
    unsigned short* __restrict__ qo, unsigned short* __restrict__ ko,
    unsigned short* __restrict__ vo)
{
  __shared__ unsigned short xs[128 * LD_];   // [token][e]
  __shared__ unsigned short wsb[64 * LD_];   // [d][e]
  __shared__ unsigned short Cl[4][32 * 72];  // per-wave repack tile

  const int tid = threadIdx.x;
  const int w = tid >> 6, lane = tid & 63;
  const int m16 = lane & 15, quad = lane >> 4;
  const int h = blockIdx.y, p = blockIdx.z;
  const int n0 = blockIdx.x * 128;           // block token base
  const unsigned short* wb = wt + (size_t)(p * H_ + h) * D_ * E_;

  const int sr = tid >> 3;          // 0..31
  const int sc = (tid & 7) * 8;     // 0,8,...,56

  f32x4 acc[2][4];
#pragma unroll
  for (int rt = 0; rt < 2; rt++)
#pragma unroll
    for (int ct = 0; ct < 4; ct++) acc[rt][ct] = (f32x4){0.f, 0.f, 0.f, 0.f};

  for (int e0 = 0; e0 < E_; e0 += 64) {
    __syncthreads();
#pragma unroll
    for (int it = 0; it < 4; it++) {
      const int row = it * 32 + sr;
      *(uint4*)(xs + row * LD_ + sc) =
          *(const uint4*)(xh + (size_t)(n0 + row) * E_ + e0 + sc);
    }
#pragma unroll
    for (int it = 0; it < 2; it++) {
      const int row = it * 32 + sr;
      *(uint4*)(wsb + row * LD_ + sc) =
          *(const uint4*)(wb + (size_t)row * E_ + e0 + sc);
    }
    __syncthreads();

#pragma unroll
    for (int kk = 0; kk < 64; kk += 32) {
      U4 a0, a1, bf[4];
      a0.u = *(const uint4*)(xs + (w * 32 + m16) * LD_ + kk + quad * 8);
      a1.u = *(const uint4*)(xs + (w * 32 + 16 + m16) * LD_ + kk + quad * 8);
#pragma unroll
      for (int ct = 0; ct < 4; ct++)
        bf[ct].u = *(const uint4*)(wsb + (ct * 16 + m16) * LD_ + kk + quad * 8);
#pragma unroll
      for (int ct = 0; ct < 4; ct++) {
        acc[0][ct] = __builtin_amdgcn_mfma_f32_16x16x32_f16(a0.h, bf[ct].h, acc[0][ct], 0, 0, 0);
        acc[1][ct] = __builtin_amdgcn_mfma_f32_16x16x32_f16(a1.h, bf[ct].h, acc[1][ct], 0, 0, 0);
      }
    }
  }

  const int nw = n0 + w * 32;               // wave token base
  const int b  = n0 >> 11;                  // batch (128 | 2048, never straddles)
  const int t0 = nw & (T_ - 1);
  const size_t bh = (size_t)(b * H_ + h);

  if (p == 2) {
#pragma unroll
    for (int rt = 0; rt < 2; rt++)
#pragma unroll
      for (int ct = 0; ct < 4; ct++) {
        const int d = ct * 16 + m16;
        const int t = t0 + rt * 16 + quad * 4;
        ushort4 pk;
        pk.x = f2h(acc[rt][ct][0]); pk.y = f2h(acc[rt][ct][1]);
        pk.z = f2h(acc[rt][ct][2]); pk.w = f2h(acc[rt][ct][3]);
        *(ushort4*)(vo + (bh * D_ + d) * (size_t)VTS_ + t) = pk;
      }
  } else {
    unsigned short* outp = (p == 0) ? qo : ko;
    unsigned short* Cw = &Cl[w][0];
#pragma unroll
    for (int rt = 0; rt < 2; rt++)
#pragma unroll
      for (int ct = 0; ct < 4; ct++)
#pragma unroll
        for (int r = 0; r < 4; r++)
          Cw[(rt * 16 + quad * 4 + r) * 72 + ct * 16 + m16] = f2h(acc[rt][ct][r]);
    const int row = lane >> 1;
    const int half = (lane & 1) * 32;
    const uint4 d0 = *(const uint4*)(Cw + row * 72 + half);
    const uint4 d1 = *(const uint4*)(Cw + row * 72 + half + 8);
    const uint4 d2 = *(const uint4*)(Cw + row * 72 + half + 16);
    const uint4 d3 = *(const uint4*)(Cw + row * 72 + half + 24);
    unsigned short* dst = outp + (bh * T_ + t0 + row) * D_ + half;
    *(uint4*)(dst)      = d0;
    *(uint4*)(dst + 8)  = d1;
    *(uint4*)(dst + 16) = d2;
    *(uint4*)(dst + 24) = d3;
  }
}

// ---------------------------------------------------------------------------
// Kernel 2: MFMA flash attention (round-17).
// grid = 512 flat (XCD-swizzled), block = 512 (8 waves = 8 Q-tiles of 16).
// KV tile = 64, LDS double-buffered (36.9KB -> 2 blocks/CU, 16 waves/CU).
// V staged permuted: key=ctk*16+quad*4+r stored at col'=quad*16+ctk*4+r,
// so PV B-fragments come from 2x b128 per ctd (8 reads/tile, conflict-free).
// Softmax in exp2 domain (0.125*log2e pre-folded into Wq).
// ---------------------------------------------------------------------------
__global__ __launch_bounds__(512) void attn_kernel(
    const unsigned short* __restrict__ q, const unsigned short* __restrict__ k,
    const unsigned short* __restrict__ vt, unsigned short* __restrict__ comb)
{
  __shared__ unsigned short Kt[2][64 * LD_];   // [key][d]
  __shared__ unsigned short Vt[2][64 * LD_];   // [d][key-permuted]

  const int tid  = threadIdx.x;
  const int w    = tid >> 6;          // 0..7
  const int lane = tid & 63;
  const int m16  = lane & 15;
  const int quad = lane >> 4;

  // XCD-bijective swizzle: XCD i (= flat%8) serves swz in [i*64, (i+1)*64)
  // = 4 whole (b,h) groups -> K/V/Q ~3.1MB fits that XCD's 4MB L2.
  const int flat = blockIdx.x;                   // 0..511
  const int swz  = (flat & 7) * 64 + (flat >> 3);
  const int xq   = swz & 15;
  const int h    = (swz >> 4) & 15;
  const int b    = swz >> 8;

  const size_t bh = (size_t)(b * H_ + h);
  const int q0 = xq * 128 + w * 16;

  // Q fragments (already scaled by 0.125*log2e via Wq folding).
  U4 aQ0, aQ1;
  {
    const unsigned short* qrow = q + (bh * T_ + q0 + m16) * (size_t)D_;
    aQ0.u = *(const uint4*)(qrow + quad * 8);
    aQ1.u = *(const uint4*)(qrow + 32 + quad * 8);
  }

  f32x4 o[4];
#pragma unroll
  for (int i = 0; i < 4; i++) o[i] = (f32x4){0.f, 0.f, 0.f, 0.f};
  float mrow = -1e30f;   // running max (log2 units) of q-row m16
  float lrow = 0.f;      // running denom of q-row m16

  // staging: 512 threads, one uint4 each for K and V per tile.
  const int sr = tid >> 3;          // 0..63
  const int sc = (tid & 7) * 8;     // 0,8,...,56
  // permuted V dest for source keys sc..sc+3 (and +16 for keys sc+4..sc+7)
  const int vdoff = ((sc >> 2) & 3) * 16 + (sc >> 4) * 4;

  const unsigned short* kp = k  + bh * (size_t)(T_ * D_)   + (size_t)sr * D_ + sc;
  const unsigned short* vp = vt + bh * (size_t)(D_ * VTS_) + (size_t)sr * VTS_ + sc;

  uint4 kr, vr;
  // prologue: stage tile 0
  kr = *(const uint4*)(kp);
  vr = *(const uint4*)(vp);
  kp += 64 * D_; vp += 64;
  {
    unsigned short* kd = &Kt[0][0] + sr * LD_ + sc;
    unsigned short* vd = &Vt[0][0] + sr * LD_ + vdoff;
    *(uint4*)(kd) = kr;
    *(uint2*)(vd)      = make_uint2(vr.x, vr.y);
    *(uint2*)(vd + 16) = make_uint2(vr.z, vr.w);
  }
  __syncthreads();

  const int NT = T_ / 64;
  for (int t = 0; t < NT; t++) {
    const int cur = t & 1;
    const unsigned short* Kc = &Kt[cur][0];
    const unsigned short* Vc = &Vt[cur][0];
    const bool more = (t + 1 < NT);
    if (more) {   // issue next tile a full compute early
      kr = *(const uint4*)(kp);
      vr = *(const uint4*)(vp);
      kp += 64 * D_; vp += 64;
    }

    // QK^T swapped: st[ct][r] = S[q=m16][key = ct*16 + quad*4 + r] (log2-scaled)
    f32x4 st[4];
#pragma unroll
    for (int ct = 0; ct < 4; ct++) {
      U4 kf0, kf1;
      kf0.u = *(const uint4*)(Kc + (ct * 16 + m16) * LD_ + quad * 8);
      kf1.u = *(const uint4*)(Kc + (ct * 16 + m16) * LD_ + 32 + quad * 8);
      f32x4 z = {0.f, 0.f, 0.f, 0.f};
      z = __builtin_amdgcn_mfma_f32_16x16x32_f16(kf0.h, aQ0.h, z, 0, 0, 0);
      z = __builtin_amdgcn_mfma_f32_16x16x32_f16(kf1.h, aQ1.h, z, 0, 0, 0);
      st[ct] = z;
    }

    // row max: lane-local tree over 16 keys, then combine across quads
    const float m0 = fmaxf(fmaxf(st[0][0], st[0][1]), fmaxf(st[0][2], st[0][3]));
    const float m1 = fmaxf(fmaxf(st[1][0], st[1][1]), fmaxf(st[1][2], st[1][3]));
    const float m2 = fmaxf(fmaxf(st[2][0], st[2][1]), fmaxf(st[2][2], st[2][3]));
    const float m3 = fmaxf(fmaxf(st[3][0], st[3][1]), fmaxf(st[3][2], st[3][3]));
    float ml = fmaxf(fmaxf(m0, m1), fmaxf(m2, m3));
    ml = fmaxf(ml, __shfl_xor(ml, 16));
    ml = fmaxf(ml, __shfl_xor(ml, 32));

    // defer-max: rescale only when some row grew by > 11 bits (P <= 2^11)
    if (!__all(ml - mrow <= 11.0f)) {
      const float mn2 = fmaxf(mrow, ml);
      const float a   = fexp2(mrow - mn2);
      float al[4];
#pragma unroll
      for (int r = 0; r < 4; r++) al[r] = __shfl(a, quad * 4 + r);
#pragma unroll
      for (int i = 0; i < 4; i++)
#pragma unroll
        for (int r = 0; r < 4; r++) o[i][r] *= al[r];
      lrow *= a;
      mrow = mn2;
    }
    const float mn = mrow;

    // exp2 + row sum; packed values directly form PV A-fragments
    float sl = 0.f;
    h4 pf[4];
#pragma unroll
    for (int ct = 0; ct < 4; ct++) {
      const float e0 = fexp2(st[ct][0] - mn);
      const float e1 = fexp2(st[ct][1] - mn);
      const float e2 = fexp2(st[ct][2] - mn);
      const float e3 = fexp2(st[ct][3] - mn);
      sl += (e0 + e1) + (e2 + e3);
      pf[ct] = (h4){(_Float16)e0, (_Float16)e1, (_Float16)e2, (_Float16)e3};
    }
    sl += __shfl_xor(sl, 16);
    sl += __shfl_xor(sl, 32);
    lrow += sl;

    // PV: 16x16x16 MFMAs; two b128 per ctd yield the 4 ctk fragments
    // (permuted layout; conflict-free by bank analysis).
#pragma unroll
    for (int ctd = 0; ctd < 4; ctd++) {
      const unsigned short* vrow = Vc + (ctd * 16 + m16) * LD_ + quad * 16;
      V8 va, vb;
      va.u = *(const uint4*)(vrow);
      vb.u = *(const uint4*)(vrow + 8);
      o[ctd] = __builtin_amdgcn_mfma_f32_16x16x16f16(pf[0], va.f[0], o[ctd], 0, 0, 0);
      o[ctd] = __builtin_amdgcn_mfma_f32_16x16x16f16(pf[1], va.f[1], o[ctd], 0, 0, 0);
      o[ctd] = __builtin_amdgcn_mfma_f32_16x16x16f16(pf[2], vb.f[0], o[ctd], 0, 0, 0);
      o[ctd] = __builtin_amdgcn_mfma_f32_16x16x16f16(pf[3], vb.f[1], o[ctd], 0, 0, 0);
    }

    if (more) {
      __syncthreads();   // all waves done reading buf[cur^1] (tile t-1)
      unsigned short* kd = &Kt[cur ^ 1][0] + sr * LD_ + sc;
      unsigned short* vd = &Vt[cur ^ 1][0] + sr * LD_ + vdoff;
      *(uint4*)(kd) = kr;
      *(uint2*)(vd)      = make_uint2(vr.x, vr.y);
      *(uint2*)(vd + 16) = make_uint2(vr.z, vr.w);
      __syncthreads();   // writes visible before compute(t+1)
    }
  }

  float linv[4];
#pragma unroll
  for (int r = 0; r < 4; r++) linv[r] = 1.f / __shfl(lrow, quad * 4 + r);

#pragma unroll
  for (int r = 0; r < 4; r++) {
    const int tq = q0 + quad * 4 + r;
    unsigned short* dst = comb + ((size_t)b * T_ + tq) * E_ + h * D_;
    dst[m16]      = f2h(o[0][r] * linv[r]);
    dst[16 + m16] = f2h(o[1][r] * linv[r]);
    dst[32 + m16] = f2h(o[2][r] * linv[r]);
    dst[48 + m16] = f2h(o[3][r] * linv[r]);
  }
}

// ---------------------------------------------------------------------------
// Kernel 3: out = comb @ Wo + x, coalesced LDS staging.
// grid=(B*T/128, E/64), block=256 (4 waves). Block: 128 n x 64 j.
// ---------------------------------------------------------------------------
__global__ __launch_bounds__(256) void out_mfma(
    const unsigned short* __restrict__ comb, const unsigned short* __restrict__ wot,
    const float* __restrict__ x, float* __restrict__ out)
{
  __shared__ unsigned short cs[128 * LD_];   // [n][e]
  __shared__ unsigned short wsb[64 * LD_];   // [j][e]

  const int tid = threadIdx.x;
  const int w = tid >> 6, lane = tid & 63;
  const int m16 = lane & 15, quad = lane >> 4;
  const int n0 = blockIdx.x * 128;
  const int j0 = blockIdx.y * 64;

  const int sr = tid >> 3;          // 0..31
  const int sc = (tid & 7) * 8;     // 0,8,...,56

  f32x4 acc[2][4];
#pragma unroll
  for (int rt = 0; rt < 2; rt++)
#pragma unroll
    for (int ct = 0; ct < 4; ct++) acc[rt][ct] = (f32x4){0.f, 0.f, 0.f, 0.f};

  for (int e0 = 0; e0 < E_; e0 += 64) {
    __syncthreads();
#pragma unroll
    for (int it = 0; it < 4; it++) {
      const int row = it * 32 + sr;
      *(uint4*)(cs + row * LD_ + sc) =
          *(const uint4*)(comb + (size_t)(n0 + row) * E_ + e0 + sc);
    }
#pragma unroll
    for (int it = 0; it < 2; it++) {
      const int row = it * 32 + sr;
      *(uint4*)(wsb + row * LD_ + sc) =
          *(const uint4*)(wot + (size_t)(j0 + row) * E_ + e0 + sc);
    }
    __syncthreads();

#pragma unroll
    for (int kk = 0; kk < 64; kk += 32) {
      U4 a0, a1, bf[4];
      a0.u = *(const uint4*)(cs + (w * 32 + m16) * LD_ + kk + quad * 8);
      a1.u = *(const uint4*)(cs + (w * 32 + 16 + m16) * LD_ + kk + quad * 8);
#pragma unroll
      for (int ct = 0; ct < 4; ct++)
        bf[ct].u = *(const uint4*)(wsb + (ct * 16 + m16) * LD_ + kk + quad * 8);
#pragma unroll
      for (int ct = 0; ct < 4; ct++) {
        acc[0][ct] = __builtin_amdgcn_mfma_f32_16x16x32_f16(a0.h, bf[ct].h, acc[0][ct], 0, 0, 0);
        acc[1][ct] = __builtin_amdgcn_mfma_f32_16x16x32_f16(a1.h, bf[ct].h, acc[1][ct], 0, 0, 0);
      }
    }
  }

  const int nw = n0 + w * 32;
#pragma unroll
  for (int rt = 0; rt < 2; rt++)
#pragma unroll
    for (int r = 0; r < 4; r++) {
      const int n = nw + rt * 16 + quad * 4 + r;
      const float* xr = x + (size_t)n * E_ + j0;
      float* orow = out + (size_t)n * E_ + j0;
#pragma unroll
      for (int ct = 0; ct < 4; ct++) {
        const int j = ct * 16 + m16;
        orow[j] = acc[rt][ct][r] + xr[j];
      }
    }
}

// ---------------------------------------------------------------------------
extern "C" void kernel_launch(void* const* d_in, const int* in_sizes, int n_in,
                              void* d_out, int out_size, void* d_ws, size_t ws_size,
                              hipStream_t stream) {
  (void)in_sizes; (void)n_in; (void)out_size; (void)ws_size;

  const float* x  = (const float*)d_in[0];
  const float* Wq = (const float*)d_in[1];
  const float* Wk = (const float*)d_in[2];
  const float* Wv = (const float*)d_in[3];
  const float* Wo = (const float*)d_in[4];
  float* out = (float*)d_out;

  unsigned short* ws0  = (unsigned short*)d_ws;
  unsigned short* xh   = ws0;                    // 4M elems (aliases comb)
  unsigned short* wt   = ws0 + 4194304;          // 3M
  unsigned short* wot  = ws0 + 7340032;          // 1M
  unsigned short* qh   = ws0 + 8388608;          // 4M
  unsigned short* kh   = ws0 + 12582912;         // 4M
  unsigned short* vth  = ws0 + 16777216;         // 32*64*2176 = 4.46M (padded)
  unsigned short* comb = xh;                     // alias: xh dead after qkv

  cvt_x<<<dim3(B_ * T_ * E_ / 1024), dim3(256), 0, stream>>>(x, xh);
  tconv_w<<<dim3(E_ / 64, H_, 3), dim3(256), 0, stream>>>(Wq, Wk, Wv, wt);
  tconv_wo<<<dim3(E_ / 64, E_ / 64), dim3(256), 0, stream>>>(Wo, wot);

  qkv_mfma<<<dim3(B_ * T_ / 128, H_, 3), dim3(256), 0, stream>>>(xh, wt, qh, kh, vth);

  attn_kernel<<<dim3(B_ * H_ * (T_ / 128)), dim3(512), 0, stream>>>(qh, kh, vth, comb);

  out_mfma<<<dim3(B_ * T_ / 128, E_ / 64), dim3(256), 0, stream>>>(comb, wot, x, out);
}

// Round 8
// 205.486 us; speedup vs baseline: 1.4809x; 1.0038x over previous
//
#include <hip/hip_runtime.h>
#include <hip/hip_bf16.h>

// MultiAttentionHead: B=2, T=2048, E=1024, H=16, D=64
// Inputs (fp32): x[B,T,E], Wq[H,E,D], Wk[H,E,D], Wv[H,E,D], Wo[E,E]
// Output (fp32): combined @ Wo + x   [B,T,E]
//
// r11: attn softmax fully in-register (swapped QK^T; exp'd values feed PV
//      directly). r12-r14: KV=128 spilled -> stay at KV=64 footprint.
// r15: XCD-bijective swizzle (FETCH 70->12MB) + defer-max. 86.2us attn.
// r17: 8-wave attn blocks + permuted V (PV = 8x b128 conflict-free) + exp2
//      softmax (scale folded into Wq). attn 67.8us, Mfma 31%, VALU 44%.
// r18 (this round): attn is no longer dominant (68 of 206us). qkv_mfma is
//      the biggest remaining chunk (~55-60us est): LDS-pipe/staging-bound
//      (12 ds_read_b128 vs 16 MFMA per wave-step, 2 barriers per 64-K).
//      -> 256-token x 64-out blocks, 512 thr (8 waves), grid (16,16,3) =
//      768 = 3 blocks/CU (46.1KB LDS). Per-wave inner loop byte-identical
//      (no spill risk); W-staging + barriers per token HALVE. Q/K repack
//      reuses xs (dead after K-loop) to avoid an LDS occupancy cliff.

#define B_ 2
#define T_ 2048
#define E_ 1024
#define H_ 16
#define D_ 64
#define VTS_ 2176   // padded vt leading dim (elements)
#define LD_ 72      // LDS tile row stride (elements; 64 + 8, keeps 16B align)

typedef _Float16 h8 __attribute__((ext_vector_type(8)));
typedef _Float16 h4 __attribute__((ext_vector_type(4)));
typedef float f32x4 __attribute__((ext_vector_type(4)));

union U4 { uint4 u; h8 h; };
union V8 { uint4 u; h4 f[2]; };   // 16 bytes = 8 halves = 2 PV B-fragments

__device__ __forceinline__ float h2f(unsigned short s) {
  _Float16 h;
  __builtin_memcpy(&h, &s, 2);
  return (float)h;
}

__device__ __forceinline__ unsigned short f2h(float f) {
  _Float16 h = (_Float16)f;
  unsigned short s;
  __builtin_memcpy(&s, &h, 2);
  return s;
}

// exp2 via v_exp_f32 when available; mathematically-identical fallback.
__device__ __forceinline__ float fexp2(float x) {
#if __has_builtin(__builtin_amdgcn_exp2f)
  return __builtin_amdgcn_exp2f(x);
#else
  return __expf(x * 0.6931471805599453f);
#endif
}

// ---------------------------------------------------------------------------
// Prep 0: x fp32 -> fp16.  grid = B*T*E/1024, block=256.
// ---------------------------------------------------------------------------
__global__ __launch_bounds__(256) void cvt_x(const float* __restrict__ x,
                                             unsigned short* __restrict__ xh) {
  const size_t i = ((size_t)blockIdx.x * 256 + threadIdx.x) * 4;
  const float4 f = *(const float4*)(x + i);
  ushort4 pk;
  pk.x = f2h(f.x); pk.y = f2h(f.y); pk.z = f2h(f.z); pk.w = f2h(f.w);
  *(ushort4*)(xh + i) = pk;
}

// ---------------------------------------------------------------------------
// Prep 1: Wq/Wk/Wv [h][e][d] fp32 -> wt [p][h][d][e] fp16. grid=(16,16,3).
// Wq additionally scaled by 0.125*log2e (softmax runs in exp2 domain).
// ---------------------------------------------------------------------------
__global__ __launch_bounds__(256) void tconv_w(
    const float* __restrict__ Wq, const float* __restrict__ Wk,
    const float* __restrict__ Wv, unsigned short* __restrict__ wt) {
  __shared__ float ts[64][65];
  const int p = blockIdx.z, h = blockIdx.y;
  const float* src = ((p == 0) ? Wq : (p == 1) ? Wk : Wv) + (size_t)h * E_ * D_;
  unsigned short* dst = wt + (size_t)(p * H_ + h) * D_ * E_;
  const float scl = (p == 0) ? 0.18033688011112042f : 1.0f;  // 0.125*log2(e)
  const int r0 = blockIdx.x * 64;  // e-tile
  const int lr = threadIdx.x >> 4, lc = (threadIdx.x & 15) * 4;
#pragma unroll
  for (int it = 0; it < 4; it++) {
    const float4 f = *(const float4*)(src + (size_t)(r0 + lr + it * 16) * D_ + lc);
    ts[lr + it * 16][lc] = f.x * scl; ts[lr + it * 16][lc + 1] = f.y * scl;
    ts[lr + it * 16][lc + 2] = f.z * scl; ts[lr + it * 16][lc + 3] = f.w * scl;
  }
  __syncthreads();
#pragma unroll
  for (int it = 0; it < 4; it++) {
    const int dr = lr + it * 16;  // d
    ushort4 pk;
    pk.x = f2h(ts[lc + 0][dr]); pk.y = f2h(ts[lc + 1][dr]);
    pk.z = f2h(ts[lc + 2][dr]); pk.w = f2h(ts[lc + 3][dr]);
    *(ushort4*)(dst + (size_t)dr * E_ + r0 + lc) = pk;
  }
}

// ---------------------------------------------------------------------------
// Prep 2: Wo [e][j] fp32 -> wot [j][e] fp16. grid=(16,16).
// ---------------------------------------------------------------------------
__global__ __launch_bounds__(256) void tconv_wo(const float* __restrict__ Wo,
                                                unsigned short* __restrict__ wot) {
  __shared__ float ts[64][65];
  const int r0 = blockIdx.x * 64;  // e-tile
  const int c0 = blockIdx.y * 64;  // j-tile
  const int lr = threadIdx.x >> 4, lc = (threadIdx.x & 15) * 4;
#pragma unroll
  for (int it = 0; it < 4; it++) {
    const float4 f = *(const float4*)(Wo + (size_t)(r0 + lr + it * 16) * E_ + c0 + lc);
    ts[lr + it * 16][lc] = f.x; ts[lr + it * 16][lc + 1] = f.y;
    ts[lr + it * 16][lc + 2] = f.z; ts[lr + it * 16][lc + 3] = f.w;
  }
  __syncthreads();
#pragma unroll
  for (int it = 0; it < 4; it++) {
    const int dr = lr + it * 16;  // j within tile
    ushort4 pk;
    pk.x = f2h(ts[lc + 0][dr]); pk.y = f2h(ts[lc + 1][dr]);
    pk.z = f2h(ts[lc + 2][dr]); pk.w = f2h(ts[lc + 3][dr]);
    *(ushort4*)(wot + (size_t)(c0 + dr) * E_ + r0 + lc) = pk;
  }
}

// ---------------------------------------------------------------------------
// Kernel 1: QKV projections via MFMA (round-18).
// grid=(B*T/256, H, 3), block=512 (8 waves). Block: 256 tokens x 64 outs.
// Per-wave inner loop identical to the proven 4-wave version; W-staging and
// barrier counts per token halved. Epilogue repack reuses xs (dead).
// ---------------------------------------------------------------------------
__global__ __launch_bounds__(512) void qkv_mfma(
    const unsigned short* __restrict__ xh, const unsigned short* __restrict__ wt,
    unsigned short* __restrict__ qo, unsigned short* __restrict__ ko,
    unsigned short* __restrict__ vo)
{
  __shared__ unsigned short xs[256 * LD_];   // [token][e]; epilogue: repack
  __shared__ unsigned short wsb[64 * LD_];   // [d][e]

  const int tid = threadIdx.x;
  const int w = tid >> 6, lane = tid & 63;
  const int m16 = lane & 15, quad = lane >> 4;
  const int h = blockIdx.y, p = blockIdx.z;
  const int n0 = blockIdx.x * 256;           // block token base
  const unsigned short* wb = wt + (size_t)(p * H_ + h) * D_ * E_;

  const int sr = tid >> 3;          // 0..63
  const int sc = (tid & 7) * 8;     // 0,8,...,56

  f32x4 acc[2][4];
#pragma unroll
  for (int rt = 0; rt < 2; rt++)
#pragma unroll
    for (int ct = 0; ct < 4; ct++) acc[rt][ct] = (f32x4){0.f, 0.f, 0.f, 0.f};

  for (int e0 = 0; e0 < E_; e0 += 64) {
    __syncthreads();
#pragma unroll
    for (int it = 0; it < 4; it++) {
      const int row = it * 64 + sr;
      *(uint4*)(xs + row * LD_ + sc) =
          *(const uint4*)(xh + (size_t)(n0 + row) * E_ + e0 + sc);
    }
    *(uint4*)(wsb + sr * LD_ + sc) =
        *(const uint4*)(wb + (size_t)sr * E_ + e0 + sc);
    __syncthreads();

#pragma unroll
    for (int kk = 0; kk < 64; kk += 32) {
      U4 a0, a1, bf[4];
      a0.u = *(const uint4*)(xs + (w * 32 + m16) * LD_ + kk + quad * 8);
      a1.u = *(const uint4*)(xs + (w * 32 + 16 + m16) * LD_ + kk + quad * 8);
#pragma unroll
      for (int ct = 0; ct < 4; ct++)
        bf[ct].u = *(const uint4*)(wsb + (ct * 16 + m16) * LD_ + kk + quad * 8);
#pragma unroll
      for (int ct = 0; ct < 4; ct++) {
        acc[0][ct] = __builtin_amdgcn_mfma_f32_16x16x32_f16(a0.h, bf[ct].h, acc[0][ct], 0, 0, 0);
        acc[1][ct] = __builtin_amdgcn_mfma_f32_16x16x32_f16(a1.h, bf[ct].h, acc[1][ct], 0, 0, 0);
      }
    }
  }

  const int nw = n0 + w * 32;               // wave token base
  const int b  = n0 >> 11;                  // batch (256 | 2048, never straddles)
  const int t0 = nw & (T_ - 1);
  const size_t bh = (size_t)(b * H_ + h);

  if (p == 2) {
#pragma unroll
    for (int rt = 0; rt < 2; rt++)
#pragma unroll
      for (int ct = 0; ct < 4; ct++) {
        const int d = ct * 16 + m16;
        const int t = t0 + rt * 16 + quad * 4;
        ushort4 pk;
        pk.x = f2h(acc[rt][ct][0]); pk.y = f2h(acc[rt][ct][1]);
        pk.z = f2h(acc[rt][ct][2]); pk.w = f2h(acc[rt][ct][3]);
        *(ushort4*)(vo + (bh * D_ + d) * (size_t)VTS_ + t) = pk;
      }
  } else {
    unsigned short* outp = (p == 0) ? qo : ko;
    __syncthreads();                        // xs reads of last e0 done
    unsigned short* Cw = xs + w * (32 * 72);  // reuse xs: 8*32*72 = 18432 ✓
#pragma unroll
    for (int rt = 0; rt < 2; rt++)
#pragma unroll
      for (int ct = 0; ct < 4; ct++)
#pragma unroll
        for (int r = 0; r < 4; r++)
          Cw[(rt * 16 + quad * 4 + r) * 72 + ct * 16 + m16] = f2h(acc[rt][ct][r]);
    const int row = lane >> 1;
    const int half = (lane & 1) * 32;
    const uint4 d0 = *(const uint4*)(Cw + row * 72 + half);
    const uint4 d1 = *(const uint4*)(Cw + row * 72 + half + 8);
    const uint4 d2 = *(const uint4*)(Cw + row * 72 + half + 16);
    const uint4 d3 = *(const uint4*)(Cw + row * 72 + half + 24);
    unsigned short* dst = outp + (bh * T_ + t0 + row) * D_ + half;
    *(uint4*)(dst)      = d0;
    *(uint4*)(dst + 8)  = d1;
    *(uint4*)(dst + 16) = d2;
    *(uint4*)(dst + 24) = d3;
  }
}

// ---------------------------------------------------------------------------
// Kernel 2: MFMA flash attention (round-17, unchanged).
// grid = 512 flat (XCD-swizzled), block = 512 (8 waves = 8 Q-tiles of 16).
// ---------------------------------------------------------------------------
__global__ __launch_bounds__(512) void attn_kernel(
    const unsigned short* __restrict__ q, const unsigned short* __restrict__ k,
    const unsigned short* __restrict__ vt, unsigned short* __restrict__ comb)
{
  __shared__ unsigned short Kt[2][64 * LD_];   // [key][d]
  __shared__ unsigned short Vt[2][64 * LD_];   // [d][key-permuted]

  const int tid  = threadIdx.x;
  const int w    = tid >> 6;          // 0..7
  const int lane = tid & 63;
  const int m16  = lane & 15;
  const int quad = lane >> 4;

  const int flat = blockIdx.x;                   // 0..511
  const int swz  = (flat & 7) * 64 + (flat >> 3);
  const int xq   = swz & 15;
  const int h    = (swz >> 4) & 15;
  const int b    = swz >> 8;

  const size_t bh = (size_t)(b * H_ + h);
  const int q0 = xq * 128 + w * 16;

  U4 aQ0, aQ1;
  {
    const unsigned short* qrow = q + (bh * T_ + q0 + m16) * (size_t)D_;
    aQ0.u = *(const uint4*)(qrow + quad * 8);
    aQ1.u = *(const uint4*)(qrow + 32 + quad * 8);
  }

  f32x4 o[4];
#pragma unroll
  for (int i = 0; i < 4; i++) o[i] = (f32x4){0.f, 0.f, 0.f, 0.f};
  float mrow = -1e30f;   // running max (log2 units) of q-row m16
  float lrow = 0.f;      // running denom of q-row m16

  const int sr = tid >> 3;          // 0..63
  const int sc = (tid & 7) * 8;     // 0,8,...,56
  const int vdoff = ((sc >> 2) & 3) * 16 + (sc >> 4) * 4;

  const unsigned short* kp = k  + bh * (size_t)(T_ * D_)   + (size_t)sr * D_ + sc;
  const unsigned short* vp = vt + bh * (size_t)(D_ * VTS_) + (size_t)sr * VTS_ + sc;

  uint4 kr, vr;
  kr = *(const uint4*)(kp);
  vr = *(const uint4*)(vp);
  kp += 64 * D_; vp += 64;
  {
    unsigned short* kd = &Kt[0][0] + sr * LD_ + sc;
    unsigned short* vd = &Vt[0][0] + sr * LD_ + vdoff;
    *(uint4*)(kd) = kr;
    *(uint2*)(vd)      = make_uint2(vr.x, vr.y);
    *(uint2*)(vd + 16) = make_uint2(vr.z, vr.w);
  }
  __syncthreads();

  const int NT = T_ / 64;
  for (int t = 0; t < NT; t++) {
    const int cur = t & 1;
    const unsigned short* Kc = &Kt[cur][0];
    const unsigned short* Vc = &Vt[cur][0];
    const bool more = (t + 1 < NT);
    if (more) {   // issue next tile a full compute early
      kr = *(const uint4*)(kp);
      vr = *(const uint4*)(vp);
      kp += 64 * D_; vp += 64;
    }

    f32x4 st[4];
#pragma unroll
    for (int ct = 0; ct < 4; ct++) {
      U4 kf0, kf1;
      kf0.u = *(const uint4*)(Kc + (ct * 16 + m16) * LD_ + quad * 8);
      kf1.u = *(const uint4*)(Kc + (ct * 16 + m16) * LD_ + 32 + quad * 8);
      f32x4 z = {0.f, 0.f, 0.f, 0.f};
      z = __builtin_amdgcn_mfma_f32_16x16x32_f16(kf0.h, aQ0.h, z, 0, 0, 0);
      z = __builtin_amdgcn_mfma_f32_16x16x32_f16(kf1.h, aQ1.h, z, 0, 0, 0);
      st[ct] = z;
    }

    const float m0 = fmaxf(fmaxf(st[0][0], st[0][1]), fmaxf(st[0][2], st[0][3]));
    const float m1 = fmaxf(fmaxf(st[1][0], st[1][1]), fmaxf(st[1][2], st[1][3]));
    const float m2 = fmaxf(fmaxf(st[2][0], st[2][1]), fmaxf(st[2][2], st[2][3]));
    const float m3 = fmaxf(fmaxf(st[3][0], st[3][1]), fmaxf(st[3][2], st[3][3]));
    float ml = fmaxf(fmaxf(m0, m1), fmaxf(m2, m3));
    ml = fmaxf(ml, __shfl_xor(ml, 16));
    ml = fmaxf(ml, __shfl_xor(ml, 32));

    if (!__all(ml - mrow <= 11.0f)) {
      const float mn2 = fmaxf(mrow, ml);
      const float a   = fexp2(mrow - mn2);
      float al[4];
#pragma unroll
      for (int r = 0; r < 4; r++) al[r] = __shfl(a, quad * 4 + r);
#pragma unroll
      for (int i = 0; i < 4; i++)
#pragma unroll
        for (int r = 0; r < 4; r++) o[i][r] *= al[r];
      lrow *= a;
      mrow = mn2;
    }
    const float mn = mrow;

    float sl = 0.f;
    h4 pf[4];
#pragma unroll
    for (int ct = 0; ct < 4; ct++) {
      const float e0 = fexp2(st[ct][0] - mn);
      const float e1 = fexp2(st[ct][1] - mn);
      const float e2 = fexp2(st[ct][2] - mn);
      const float e3 = fexp2(st[ct][3] - mn);
      sl += (e0 + e1) + (e2 + e3);
      pf[ct] = (h4){(_Float16)e0, (_Float16)e1, (_Float16)e2, (_Float16)e3};
    }
    sl += __shfl_xor(sl, 16);
    sl += __shfl_xor(sl, 32);
    lrow += sl;

#pragma unroll
    for (int ctd = 0; ctd < 4; ctd++) {
      const unsigned short* vrow = Vc + (ctd * 16 + m16) * LD_ + quad * 16;
      V8 va, vb;
      va.u = *(const uint4*)(vrow);
      vb.u = *(const uint4*)(vrow + 8);
      o[ctd] = __builtin_amdgcn_mfma_f32_16x16x16f16(pf[0], va.f[0], o[ctd], 0, 0, 0);
      o[ctd] = __builtin_amdgcn_mfma_f32_16x16x16f16(pf[1], va.f[1], o[ctd], 0, 0, 0);
      o[ctd] = __builtin_amdgcn_mfma_f32_16x16x16f16(pf[2], vb.f[0], o[ctd], 0, 0, 0);
      o[ctd] = __builtin_amdgcn_mfma_f32_16x16x16f16(pf[3], vb.f[1], o[ctd], 0, 0, 0);
    }

    if (more) {
      __syncthreads();
      unsigned short* kd = &Kt[cur ^ 1][0] + sr * LD_ + sc;
      unsigned short* vd = &Vt[cur ^ 1][0] + sr * LD_ + vdoff;
      *(uint4*)(kd) = kr;
      *(uint2*)(vd)      = make_uint2(vr.x, vr.y);
      *(uint2*)(vd + 16) = make_uint2(vr.z, vr.w);
      __syncthreads();
    }
  }

  float linv[4];
#pragma unroll
  for (int r = 0; r < 4; r++) linv[r] = 1.f / __shfl(lrow, quad * 4 + r);

#pragma unroll
  for (int r = 0; r < 4; r++) {
    const int tq = q0 + quad * 4 + r;
    unsigned short* dst = comb + ((size_t)b * T_ + tq) * E_ + h * D_;
    dst[m16]      = f2h(o[0][r] * linv[r]);
    dst[16 + m16] = f2h(o[1][r] * linv[r]);
    dst[32 + m16] = f2h(o[2][r] * linv[r]);
    dst[48 + m16] = f2h(o[3][r] * linv[r]);
  }
}

// ---------------------------------------------------------------------------
// Kernel 3: out = comb @ Wo + x, coalesced LDS staging.
// grid=(B*T/128, E/64), block=256 (4 waves). Block: 128 n x 64 j.
// ---------------------------------------------------------------------------
__global__ __launch_bounds__(256) void out_mfma(
    const unsigned short* __restrict__ comb, const unsigned short* __restrict__ wot,
    const float* __restrict__ x, float* __restrict__ out)
{
  __shared__ unsigned short cs[128 * LD_];   // [n][e]
  __shared__ unsigned short wsb[64 * LD_];   // [j][e]

  const int tid = threadIdx.x;
  const int w = tid >> 6, lane = tid & 63;
  const int m16 = lane & 15, quad = lane >> 4;
  const int n0 = blockIdx.x * 128;
  const int j0 = blockIdx.y * 64;

  const int sr = tid >> 3;          // 0..31
  const int sc = (tid & 7) * 8;     // 0,8,...,56

  f32x4 acc[2][4];
#pragma unroll
  for (int rt = 0; rt < 2; rt++)
#pragma unroll
    for (int ct = 0; ct < 4; ct++) acc[rt][ct] = (f32x4){0.f, 0.f, 0.f, 0.f};

  for (int e0 = 0; e0 < E_; e0 += 64) {
    __syncthreads();
#pragma unroll
    for (int it = 0; it < 4; it++) {
      const int row = it * 32 + sr;
      *(uint4*)(cs + row * LD_ + sc) =
          *(const uint4*)(comb + (size_t)(n0 + row) * E_ + e0 + sc);
    }
#pragma unroll
    for (int it = 0; it < 2; it++) {
      const int row = it * 32 + sr;
      *(uint4*)(wsb + row * LD_ + sc) =
          *(const uint4*)(wot + (size_t)(j0 + row) * E_ + e0 + sc);
    }
    __syncthreads();

#pragma unroll
    for (int kk = 0; kk < 64; kk += 32) {
      U4 a0, a1, bf[4];
      a0.u = *(const uint4*)(cs + (w * 32 + m16) * LD_ + kk + quad * 8);
      a1.u = *(const uint4*)(cs + (w * 32 + 16 + m16) * LD_ + kk + quad * 8);
#pragma unroll
      for (int ct = 0; ct < 4; ct++)
        bf[ct].u = *(const uint4*)(wsb + (ct * 16 + m16) * LD_ + kk + quad * 8);
#pragma unroll
      for (int ct = 0; ct < 4; ct++) {
        acc[0][ct] = __builtin_amdgcn_mfma_f32_16x16x32_f16(a0.h, bf[ct].h, acc[0][ct], 0, 0, 0);
        acc[1][ct] = __builtin_amdgcn_mfma_f32_16x16x32_f16(a1.h, bf[ct].h, acc[1][ct], 0, 0, 0);
      }
    }
  }

  const int nw = n0 + w * 32;
#pragma unroll
  for (int rt = 0; rt < 2; rt++)
#pragma unroll
    for (int r = 0; r < 4; r++) {
      const int n = nw + rt * 16 + quad * 4 + r;
      const float* xr = x + (size_t)n * E_ + j0;
      float* orow = out + (size_t)n * E_ + j0;
#pragma unroll
      for (int ct = 0; ct < 4; ct++) {
        const int j = ct * 16 + m16;
        orow[j] = acc[rt][ct][r] + xr[j];
      }
    }
}

// ---------------------------------------------------------------------------
extern "C" void kernel_launch(void* const* d_in, const int* in_sizes, int n_in,
                              void* d_out, int out_size, void* d_ws, size_t ws_size,
                              hipStream_t stream) {
  (void)in_sizes; (void)n_in; (void)out_size; (void)ws_size;

  const float* x  = (const float*)d_in[0];
  const float* Wq = (const float*)d_in[1];
  const float* Wk = (const float*)d_in[2];
  const float* Wv = (const float*)d_in[3];
  const float* Wo = (const float*)d_in[4];
  float* out = (float*)d_out;

  unsigned short* ws0  = (unsigned short*)d_ws;
  unsigned short* xh   = ws0;                    // 4M elems (aliases comb)
  unsigned short* wt   = ws0 + 4194304;          // 3M
  unsigned short* wot  = ws0 + 7340032;          // 1M
  unsigned short* qh   = ws0 + 8388608;          // 4M
  unsigned short* kh   = ws0 + 12582912;         // 4M
  unsigned short* vth  = ws0 + 16777216;         // 32*64*2176 = 4.46M (padded)
  unsigned short* comb = xh;                     // alias: xh dead after qkv

  cvt_x<<<dim3(B_ * T_ * E_ / 1024), dim3(256), 0, stream>>>(x, xh);
  tconv_w<<<dim3(E_ / 64, H_, 3), dim3(256), 0, stream>>>(Wq, Wk, Wv, wt);
  tconv_wo<<<dim3(E_ / 64, E_ / 64), dim3(256), 0, stream>>>(Wo, wot);

  qkv_mfma<<<dim3(B_ * T_ / 256, H_, 3), dim3(512), 0, stream>>>(xh, wt, qh, kh, vth);

  attn_kernel<<<dim3(B_ * H_ * (T_ / 128)), dim3(512), 0, stream>>>(qh, kh, vth, comb);

  out_mfma<<<dim3(B_ * T_ / 128, E_ / 64), dim3(256), 0, stream>>>(comb, wot, x, out);
}